// Round 15
// baseline (767.020 us; speedup 1.0000x reference)
//
#include <hip/hip_runtime.h>
#include <hip/hip_bf16.h>
#include <hip/hip_fp16.h>

#define VV 5000
#define NTOP 50
#define ENH 200
#define NEMB 200
#define OD 40
#define MP 5120
#define KNS 5008   // padded row stride (halfs) for scaled fp16 kernel matrix Kn

typedef __attribute__((ext_vector_type(8))) short short8;
typedef __attribute__((ext_vector_type(4))) float f32x4;

// ---------------- workspace layout (bytes) ----------------
constexpr size_t OFF_R      = 0;          // 5000 f (atomic accum, zeroed)
constexpr size_t OFF_S      = 20224;      // 512 f (atomic accum, zeroed)
constexpr size_t OFF_SCAL   = 22528;      // 64 f: [0]=eps [1]=1/eps [2]=loss_KL [3]=ecr_dot
constexpr size_t OFF_PHIA   = 22784;      // 5000 f (zeroed = phi^(0)); phi ping
constexpr size_t OFF_PHIB   = 43008;      // 5000 f; phi pong
constexpr size_t OFF_ROWS   = 63232;      // S1[40] S2[40] S3[40]
constexpr size_t OFF_PARTS  = 63744;      // ECR acc: 3 buffers x 64 f (tri-buffered, zeroed)
constexpr size_t OFF_FLAGS  = 71936;      // ECR counter: 1 int, monotone (zeroed)
constexpr size_t OFF_MUPRE  = 72960;      // 50*40 f
constexpr size_t OFF_LVPRE  = 81152;
constexpr size_t OFF_E1T    = 89344;      // 200*40 f  [k][i] (atomic accum, zeroed)
constexpr size_t OFF_E2T    = 121600;
constexpr size_t OFF_THRED  = 153856;     // 40*50 f
constexpr size_t OFF_BOWRED = 162048;     // 40*5000 f: brp slice 7 during k5; br after k5r
constexpr size_t ZERO_BYTES = 962304;     // everything below PVT is zeroed each call
constexpr size_t OFF_PVT    = 962304;     // 48*5120 bf16 (proj_V transposed, padded)
constexpr size_t OFF_XB     = 1453824;    // 5120*512 bf16 (bow.T); dead after k3 -> brp slices 0..5
constexpr size_t OFF_CE     = 6696704;    // 5000*5000 fp16 (C/eps), UPPER TRIANGLE (128-blocks) only
constexpr size_t OFF_COST   = 56696832;   // 50*5000 f; alive until ECR final (k6)
constexpr size_t OFF_KM     = 57697024;   // Kn: 50*5008 fp16 (column-max-scaled exp(-20c))
constexpr size_t OFF_BETA   = 58697216;
constexpr size_t OFF_RN     = 59697408;   // sbuf[3] during sweeps; brpC in k5; Rn after k12
// sweep row-sum tri-buffer: 3 x 5056 f at byte stride 20224 (zeroed by extra memset)

// ============ ECR block: n_iters Sinkhorn iterations, resumable across launches ============
// The PROVEN 16-block/LLC protocol. Cost model (R3/R5/R8): ~1.5-1.8us/iter marginal when
// hidden under a big host kernel; ~3.4us/iter when ECR-bound.
// Distribution: k1 10, k3 25, k4x20 2 each, k5 20, k6 5+final = 100.
__device__ __forceinline__ void ecr_block(int b, int it_base, int n_iters, bool do_final,
    const __half* __restrict__ Kn, const float* __restrict__ cost,
    float* __restrict__ acc, int* __restrict__ cnt, float* __restrict__ scal,
    char* smem){
  __half* KmL = (__half*)smem;                 // 50*322 halfs (stride 322 -> conflict-free)
  float* varr = (float*)(smem + 32208);        // 320 f, 16B aligned
  float* us   = (float*)(smem + 33488);        // 52 f
  float* p5   = (float*)(smem + 33696);        // 5*52 f
  float* redr = (float*)(smem + 34736);        // 4 f
  const int t = threadIdx.x;
  const int base = (b < 8) ? b*313 : 2504 + (b-8)*312;
  const int sz   = (b < 8) ? 313 : 312;
  for (int c = t; c < 322; c += 256){
    if (c < sz){
      #pragma unroll
      for (int q = 0; q < NTOP; ++q)
        KmL[q*322 + c] = Kn[(size_t)q*KNS + base + c];
    } else {
      #pragma unroll
      for (int q = 0; q < NTOP; ++q) KmL[q*322 + c] = __float2half(0.f);
    }
  }
  if (t < 52){
    float u0 = 0.f;
    if (t < NTOP){
      if (it_base == 0) u0 = 1.f/(float)NTOP;
      else {
        float sm = __hip_atomic_load(&acc[((it_base-1)%3)*64 + t],
                                     __ATOMIC_RELAXED, __HIP_MEMORY_SCOPE_AGENT);
        u0 = (1.f/(float)NTOP)/(sm + 1e-16f);
      }
    }
    us[t] = u0;
  }
  for (int c = sz + t; c < 320; c += 256) varr[c] = 0.f;
  __syncthreads();
  const bool act = (2*t < sz);
  for (int k = 0; k < n_iters; ++k){
    const int g = it_base + k;
    if (act){
      float w0 = 0.f, w1 = 0.f, w2 = 0.f, w3 = 0.f;
      #pragma unroll
      for (int q = 0; q < NTOP; q += 2){
        float u0 = us[q], u1 = us[q+1];
        float2 f0 = __half22float2(*(const __half2*)(KmL + q*322 + 2*t));
        float2 f1 = __half22float2(*(const __half2*)(KmL + (q+1)*322 + 2*t));
        w0 += f0.x*u0; w1 += f0.y*u0;
        w2 += f1.x*u1; w3 += f1.y*u1;
      }
      float2 vv;
      vv.x = (1.f/(float)VV)/((w0+w2) + 1e-16f);
      vv.y = (2*t+1 < sz) ? (1.f/(float)VV)/((w1+w3) + 1e-16f) : 0.f;
      *(float2*)(varr + 2*t) = vv;
    }
    __syncthreads();
    if (t < 250){
      const int qq = t % NTOP, stripe = t / NTOP;
      const __half* kp = KmL + qq*322 + stripe*64;
      const float* vp = varr + stripe*64;
      float s0 = 0.f, s1 = 0.f, s2 = 0.f, s3 = 0.f;
      #pragma unroll
      for (int n = 0; n < 64; n += 4){
        float2 fa = __half22float2(*(const __half2*)(kp + n));
        float2 fb = __half22float2(*(const __half2*)(kp + n + 2));
        float4 v4 = *(const float4*)(vp + n);
        s0 += fa.x*v4.x; s1 += fa.y*v4.y; s2 += fb.x*v4.z; s3 += fb.y*v4.w;
      }
      p5[stripe*52 + qq] = (s0+s1)+(s2+s3);
    }
    __syncthreads();
    if (t < NTOP){
      float sm = p5[t] + p5[52+t] + p5[104+t] + p5[156+t] + p5[208+t];
      __hip_atomic_fetch_add(&acc[(g%3)*64 + t], sm,
                             __ATOMIC_RELAXED, __HIP_MEMORY_SCOPE_AGENT);
    }
    __asm__ volatile("s_waitcnt vmcnt(0)" ::: "memory");
    if (t == 0){
      __hip_atomic_fetch_add(cnt, 1, __ATOMIC_RELEASE, __HIP_MEMORY_SCOPE_AGENT);
      const int tgt = 16*(g+1);
      while (__hip_atomic_load(cnt, __ATOMIC_ACQUIRE, __HIP_MEMORY_SCOPE_AGENT) < tgt)
        __builtin_amdgcn_s_sleep(1);
    }
    if (t < NTOP){
      float sm = __hip_atomic_load(&acc[(g%3)*64 + t],
                                   __ATOMIC_RELAXED, __HIP_MEMORY_SCOPE_AGENT);
      us[t] = (1.f/(float)NTOP)/(sm + 1e-16f);
    }
    if (t < 64)
      __hip_atomic_store(&acc[((g+2)%3)*64 + t], 0.f,
                         __ATOMIC_RELAXED, __HIP_MEMORY_SCOPE_AGENT);
    __syncthreads();
  }
  if (!do_final) return;
  float lsum = 0.f;
  if (act){
    float w0 = 0.f, w1 = 0.f, w2 = 0.f, w3 = 0.f;
    #pragma unroll
    for (int q = 0; q < NTOP; q += 2){
      float u0 = us[q], u1 = us[q+1];
      float2 f0 = __half22float2(*(const __half2*)(KmL + q*322 + 2*t));
      float2 f1 = __half22float2(*(const __half2*)(KmL + (q+1)*322 + 2*t));
      w0 += f0.x*u0; w1 += f0.y*u0;
      w2 += f1.x*u1; w3 += f1.y*u1;
    }
    float v0 = (1.f/(float)VV)/((w0+w2) + 1e-16f);
    const bool ok1 = (2*t+1 < sz);
    float v1 = ok1 ? (1.f/(float)VV)/((w1+w3) + 1e-16f) : 0.f;
    float accv = 0.f;
    #pragma unroll
    for (int q = 0; q < NTOP; ++q){
      float2 f = __half22float2(*(const __half2*)(KmL + q*322 + 2*t));
      float uq = us[q];
      float c0 = cost[(size_t)q*VV + base + 2*t];
      accv += uq*f.x*v0*c0;
      if (ok1){
        float c1 = cost[(size_t)q*VV + base + 2*t + 1];
        accv += uq*f.y*v1*c1;
      }
    }
    lsum = accv;
  }
  #pragma unroll
  for (int off = 32; off; off >>= 1) lsum += __shfl_down(lsum, off, 64);
  if ((t & 63) == 0) redr[t >> 6] = lsum;
  __syncthreads();
  if (t == 0) atomicAdd(&scal[3], redr[0]+redr[1]+redr[2]+redr[3]);
}

// ============ K1: transpose bow + stats; x>=40 hosts ECR iters 0..9 (16 blocks) ============
__global__ __launch_bounds__(256) void k1_stats(const float* __restrict__ bow,
    __hip_bfloat16* __restrict__ Xb, float* __restrict__ r, float* __restrict__ s,
    const __half* __restrict__ Kn, const float* __restrict__ cost,
    float* __restrict__ accg, int* __restrict__ cnt, float* __restrict__ scal){
  __shared__ __align__(16) char smem[34816];
  const int t = threadIdx.x;
  if (blockIdx.x >= 40){
    int b = (blockIdx.x - 40)*8 + blockIdx.y;
    ecr_block(b, 0, 10, false, Kn, cost, accg, cnt, scal, smem);
    return;
  }
  float (*lds)[129] = (float(*)[129])smem;   // 64*129*4 = 33024 <= 34816
  const int i0 = blockIdx.x * 128, d0 = blockIdx.y * 64;
  #pragma unroll
  for (int m = 0; m < 32; ++m){
    int idx = m*256 + t;
    int di = idx >> 7;
    int ii = idx & 127;
    int gi = i0 + ii;
    lds[di][ii] = (gi < VV) ? bow[(size_t)(d0+di)*VV + gi] : 0.f;
  }
  __syncthreads();
  if (t < 128 && (i0 + t) < VV){
    float acc = 0.f;
    for (int di = 0; di < 64; ++di){ float v = lds[di][t]; acc += v*v; }
    atomicAdd(&r[i0+t], acc);
  }
  if (t < 64){
    float acc = 0.f;
    for (int ii = 0; ii < 128; ++ii) acc += lds[t][ii];
    atomicAdd(&s[d0+t], acc);
  }
  __syncthreads();
  #pragma unroll
  for (int m = 0; m < 32; ++m){
    int idx = m*256 + t;
    int ii = idx >> 6;
    int dd = idx & 63;
    Xb[(size_t)(i0+ii)*512 + d0 + dd] = __float2bfloat16(lds[dd][ii]);
  }
}

// ============ K2: eps from closed-form mean(C) ============
__global__ __launch_bounds__(256) void k2_eps(const float* __restrict__ r,
    const float* __restrict__ s, float* __restrict__ scal){
  const int t = threadIdx.x;
  float a = 0.f, b = 0.f;
  for (int i = t; i < VV; i += 256) a += r[i];
  for (int d = t; d < 512; d += 256){ float v = s[d]; b += v*v; }
  #pragma unroll
  for (int off = 32; off; off >>= 1){
    a += __shfl_down(a, off, 64);
    b += __shfl_down(b, off, 64);
  }
  __shared__ float ra[4], rb[4];
  int lane = t & 63, w = t >> 6;
  if (lane == 0){ ra[w] = a; rb[w] = b; }
  __syncthreads();
  if (t == 0){
    float sa = ra[0]+ra[1]+ra[2]+ra[3];
    float sb = rb[0]+rb[1]+rb[2]+rb[3];
    float meanC = 2.f*sa/(float)VV - 2.f*sb/((float)VV*(float)VV);
    float eps = meanC / logf(30.f) + 1e-6f;
    scal[0] = eps;
    scal[1] = 1.f/eps;
  }
}

// ============ K3syrk: Ce GEMM, UPPER-TRIANGLE 128-blocks ONLY (820 tiles, NO mirror) ============
// R14 lesson: the mirror write cost ~25MB writes + ~10MB RFO fetches. Now the lower
// triangle is never materialized; k4 reads upper-only already, and k5 reads lower
// tiles via the stored transpose. Diagonal tiles store their full 128x128 block.
__global__ __launch_bounds__(256) void k3_gemm_ecr(const __hip_bfloat16* __restrict__ Xb,
    const float* __restrict__ r, float* __restrict__ scal, __half* __restrict__ Ce,
    const __half* __restrict__ Kn, const float* __restrict__ cost,
    float* __restrict__ accg, int* __restrict__ cnt){
  __shared__ __align__(16) char smem[36864];
  if (blockIdx.x < 16){
    ecr_block(blockIdx.x, 10, 25, false, Kn, cost, accg, cnt, scal, smem);
    return;
  }
  __hip_bfloat16* As = (__hip_bfloat16*)smem;          // 128*72
  __hip_bfloat16* Bs = (__hip_bfloat16*)(smem + 128*72*2);
  const int t = threadIdx.x;
  int bt = blockIdx.x - 16;                 // 0..819 upper-triangle tiles
  int bi = 0, rem = bt;
  while (rem >= 40 - bi){ rem -= 40 - bi; ++bi; }
  const int bj = bi + rem;
  const int i0 = bi*128, j0 = bj*128;
  const int lane = t & 63, w = t >> 6;
  const int wr = w >> 1, wc = w & 1;
  const int m16 = lane & 15, q4 = lane >> 4;
  f32x4 acc[4][4];
  #pragma unroll
  for (int a = 0; a < 4; ++a)
    #pragma unroll
    for (int b = 0; b < 4; ++b) acc[a][b] = (f32x4){0.f,0.f,0.f,0.f};
  const int srow = t >> 3, sseg = t & 7;
  for (int kc = 0; kc < 512; kc += 64){
    __syncthreads();
    #pragma unroll
    for (int m = 0; m < 4; ++m){
      int row = m*32 + srow;
      uint4 va = *(const uint4*)(Xb + (size_t)(i0+row)*512 + kc + sseg*8);
      *(uint4*)(As + row*72 + sseg*8) = va;
      uint4 vb = *(const uint4*)(Xb + (size_t)(j0+row)*512 + kc + sseg*8);
      *(uint4*)(Bs + row*72 + sseg*8) = vb;
    }
    __syncthreads();
    #pragma unroll
    for (int ks = 0; ks < 64; ks += 32){
      short8 af[4], bf[4];
      #pragma unroll
      for (int f = 0; f < 4; ++f){
        af[f] = *(const short8*)(As + (wr*64 + f*16 + m16)*72 + ks + q4*8);
        bf[f] = *(const short8*)(Bs + (wc*64 + f*16 + m16)*72 + ks + q4*8);
      }
      #pragma unroll
      for (int fr = 0; fr < 4; ++fr)
        #pragma unroll
        for (int fc = 0; fc < 4; ++fc)
          acc[fr][fc] = __builtin_amdgcn_mfma_f32_16x16x32_bf16(af[fr], bf[fc], acc[fr][fc], 0, 0, 0);
    }
  }
  const float inv_eps = scal[1];
  #pragma unroll
  for (int fr = 0; fr < 4; ++fr){
    int rbase = i0 + wr*64 + fr*16 + q4*4;
    #pragma unroll
    for (int fc = 0; fc < 4; ++fc){
      int col = j0 + wc*64 + fc*16 + m16;
      if (col < VV){
        float rc = r[col];
        #pragma unroll
        for (int q = 0; q < 4; ++q){
          int row = rbase + q;
          if (row < VV){
            float val = (r[row] + rc - 2.f*acc[fr][fc][q]) * inv_eps;
            Ce[(size_t)row*VV + col] = __float2half(val);
          }
        }
      }
    }
  }
}

// ============ K4sym: one sweep over the UPPER TRIANGLE of Ce (26 MB not 50) ============
__global__ __launch_bounds__(256) void k4_symsweep(const __half* __restrict__ Ce,
    const float* __restrict__ phi_prev, float* __restrict__ phi_cur,
    const float* __restrict__ ssum_prev, float* __restrict__ ssum_next,
    float* __restrict__ ssum_zero,
    const __half* __restrict__ Kn, const float* __restrict__ cost,
    float* __restrict__ accg, int* __restrict__ cnt, float* __restrict__ scal,
    int it_base, int g){
  __shared__ __align__(16) char smem[34816];
  const int t = threadIdx.x;
  if (blockIdx.x < 16){
    ecr_block(blockIdx.x, it_base, 2, false, Kn, cost, accg, cnt, scal, smem);
    return;
  }
  const float loga = -8.517193191416238f;   // -log(5000)
  int bt = blockIdx.x - 16;                 // 0..819 upper-triangle tiles
  int bi = 0, rem = bt;
  while (rem >= 40 - bi){ rem -= 40 - bi; ++bi; }
  const int bj = bi + rem;
  const bool diag = (bi == bj);
  const int i0 = bi*128, j0 = bj*128;
  float* phiI = (float*)smem;               // 128
  float* phiJ = (float*)smem + 128;         // 128
  float* RL   = (float*)smem + 256;         // 128*17
  if (t < 128){
    int gi = i0 + t;
    float ph = 0.f;
    if (gi < VV && g > 0)
      ph = 0.5f*(phi_prev[gi] + loga - __logf(ssum_prev[gi]));
    phiI[t] = ph;
    if (diag && gi < VV){
      phi_cur[gi] = ph;
      ssum_zero[gi] = 0.f;
    }
  } else {
    int gj = j0 + (t - 128);
    float ph = 0.f;
    if (gj < VV && g > 0)
      ph = 0.5f*(phi_prev[gj] + loga - __logf(ssum_prev[gj]));
    phiJ[t-128] = ph;
  }
  __syncthreads();
  const int rg = t >> 4, cg = t & 15;
  const int jb = j0 + cg*8;
  const bool colok = jb < VV;               // 5000 % 8 == 0 -> chunk guard exact
  float pj[8];
  #pragma unroll
  for (int e = 0; e < 8; ++e) pj[e] = phiJ[cg*8 + e];
  float rowacc[8], colacc[8];
  #pragma unroll
  for (int x = 0; x < 8; ++x){ rowacc[x] = 0.f; colacc[x] = 0.f; }
  #pragma unroll
  for (int rr = 0; rr < 8; ++rr){
    int rloc = rg*8 + rr;
    int gi = i0 + rloc;
    if (gi < VV && colok){
      uint4 v = *(const uint4*)(Ce + (size_t)gi*VV + jb);
      const __half2* hp = (const __half2*)&v;
      float pI = phiI[rloc];
      #pragma unroll
      for (int e = 0; e < 4; ++e){
        float2 c = __half22float2(hp[e]);
        rowacc[rr] += __expf(pj[2*e] - c.x) + __expf(pj[2*e+1] - c.y);
        if (!diag){
          colacc[2*e]   += __expf(pI - c.x);
          colacc[2*e+1] += __expf(pI - c.y);
        }
      }
    }
  }
  #pragma unroll
  for (int rr = 0; rr < 8; ++rr) RL[(rg*8+rr)*17 + cg] = rowacc[rr];
  __syncthreads();
  if (t < 128){
    float sm = 0.f;
    #pragma unroll
    for (int c2 = 0; c2 < 16; ++c2) sm += RL[t*17 + c2];
    int gi = i0 + t;
    if (gi < VV) atomicAdd(&ssum_next[gi], sm);
  }
  if (!diag){
    __syncthreads();
    #pragma unroll
    for (int cc = 0; cc < 8; ++cc) RL[(cg*8+cc)*17 + rg] = colacc[cc];
    __syncthreads();
    if (t < 128){
      float sm = 0.f;
      #pragma unroll
      for (int r2 = 0; r2 < 16; ++r2) sm += RL[t*17 + r2];
      int gj = j0 + t;
      if (gj < VV) atomicAdd(&ssum_next[gj], sm);
    }
  }
}

// ============ K5p: blocks 0..19 compute FINAL phi^(20); rest: proj_V -> pvt ============
__global__ __launch_bounds__(256) void k5p_pvt(const float* __restrict__ projV,
    __hip_bfloat16* __restrict__ pvt, const float* __restrict__ phi19,
    const float* __restrict__ ssum19, float* __restrict__ phiF){
  const int t = threadIdx.x;
  if (blockIdx.x < 20){
    if (t < 250){
      int i = blockIdx.x*250 + t;
      phiF[i] = 0.5f*(phi19[i] + (-8.517193191416238f) - __logf(ssum19[i]));
    }
    return;
  }
  int idx = (blockIdx.x - 20)*256 + t;
  if (idx >= 48*MP) return;
  int n = idx / MP, j = idx - n*MP;
  float v = (n < OD && j < VV) ? projV[(size_t)j*OD + n] : 0.f;
  pvt[idx] = __float2bfloat16(v);
}

// ============ K5: bow_reduced partials via MFMA + ECR iters 75..94 (x>=40) ============
// Upper-only Ce: for kc-strips strictly below the diagonal 128-block, the logical
// tile Ce[i0..][kc..] is read from the stored transpose Ce[kc..][i0..] (coalesced
// uint4 rows) and scattered into As transposed; per-lane element rotation (e+lg)&7
// spreads the stride-72 LDS writes across 8 banks (2-way conflicts only).
__global__ __launch_bounds__(256) void k5_bowred(const __half* __restrict__ Ce,
    const float* __restrict__ phi, const __hip_bfloat16* __restrict__ pvt,
    float* __restrict__ brpA, float* __restrict__ brpC, float* __restrict__ brpD,
    const __half* __restrict__ Kn, const float* __restrict__ cost,
    float* __restrict__ accg, int* __restrict__ cnt, float* __restrict__ scal){
  __shared__ __align__(16) char smem[34816];
  const int t = threadIdx.x;
  if (blockIdx.x >= 40){
    int b = (blockIdx.x - 40)*8 + blockIdx.y;
    ecr_block(b, 75, 20, false, Kn, cost, accg, cnt, scal, smem);
    return;
  }
  __hip_bfloat16* As = (__hip_bfloat16*)smem;            // 128*72
  __hip_bfloat16* Bs = (__hip_bfloat16*)(smem + 18432);  // 48*72
  const int i0 = blockIdx.x * 128;
  const int k0 = blockIdx.y * 640;
  const int lane = t & 63, w = t >> 6;
  const int m16 = lane & 15, q4 = lane >> 4;
  f32x4 acc[2][3];
  #pragma unroll
  for (int a = 0; a < 2; ++a)
    #pragma unroll
    for (int b = 0; b < 3; ++b) acc[a][b] = (f32x4){0.f,0.f,0.f,0.f};
  for (int kc = k0; kc < k0 + 640; kc += 64){
    __syncthreads();
    const bool lower = (kc >> 7) < (i0 >> 7);
    if (!lower){
      #pragma unroll
      for (int m = 0; m < 4; ++m){
        int g = m*256 + t;
        int row = g >> 3, cg = g & 7;
        int gi = i0 + row, j2 = kc + cg*8;
        union { __hip_bfloat16 h[8]; short8 v; } u;
        if (gi < VV && j2 < VV){
          uint4 vce = *(const uint4*)(Ce + (size_t)gi*VV + j2);
          const __half2* hp = (const __half2*)&vce;
          float pb = phi[gi];
          float4 pj0 = *(const float4*)(phi + j2);
          float4 pj1 = *(const float4*)(phi + j2 + 4);
          float pj[8] = {pj0.x,pj0.y,pj0.z,pj0.w,pj1.x,pj1.y,pj1.z,pj1.w};
          #pragma unroll
          for (int e = 0; e < 4; ++e){
            float2 ce = __half22float2(hp[e]);
            u.h[2*e]   = __float2bfloat16(__expf(pb + pj[2*e]   - ce.x));
            u.h[2*e+1] = __float2bfloat16(__expf(pb + pj[2*e+1] - ce.y));
          }
        } else {
          #pragma unroll
          for (int e = 0; e < 8; ++e) u.h[e] = __float2bfloat16(0.f);
        }
        *(short8*)(As + row*72 + cg*8) = u.v;
      }
    } else {
      // transposed staging from stored Ce[kc..kc+63][i0..i0+127]
      #pragma unroll
      for (int m = 0; m < 4; ++m){
        int g = m*256 + t;
        int sr = g >> 4;            // 0..63  (source row = j2 local)
        int lg = g & 15;
        int scb = lg * 8;           // 0..120 (source col base = gi local)
        int j2 = kc + sr;           // j2 < i0 <= 4992 -> valid stored row
        uint4 vce = *(const uint4*)(Ce + (size_t)j2*VV + i0 + scb);
        const __half* hp = (const __half*)&vce;
        float pj2 = phi[j2];
        #pragma unroll
        for (int e = 0; e < 8; ++e){
          int e2 = (e + lg) & 7;
          int gi = i0 + scb + e2;
          float p = 0.f;
          if (gi < VV)
            p = __expf(phi[gi] + pj2 - __half2float(hp[e2]));
          As[(scb + e2)*72 + sr] = __float2bfloat16(p);
        }
      }
    }
    #pragma unroll
    for (int m = 0; m < 12; ++m){
      int idx = m*256 + t;
      int row = idx >> 6, c = idx & 63;
      Bs[row*72 + c] = pvt[(size_t)row*MP + kc + c];
    }
    __syncthreads();
    #pragma unroll
    for (int ks = 0; ks < 64; ks += 32){
      short8 af[2], bf[3];
      #pragma unroll
      for (int f = 0; f < 2; ++f)
        af[f] = *(const short8*)(As + (w*32 + f*16 + m16)*72 + ks + q4*8);
      #pragma unroll
      for (int f = 0; f < 3; ++f)
        bf[f] = *(const short8*)(Bs + (f*16 + m16)*72 + ks + q4*8);
      #pragma unroll
      for (int fr = 0; fr < 2; ++fr)
        #pragma unroll
        for (int fc = 0; fc < 3; ++fc)
          acc[fr][fc] = __builtin_amdgcn_mfma_f32_16x16x32_bf16(af[fr], bf[fc], acc[fr][fc], 0, 0, 0);
    }
  }
  __syncthreads();
  float* LF = (float*)smem;
  #pragma unroll
  for (int fr = 0; fr < 2; ++fr){
    int lr = w*32 + fr*16 + q4*4;
    #pragma unroll
    for (int fc = 0; fc < 3; ++fc){
      int col = fc*16 + m16;
      #pragma unroll
      for (int q = 0; q < 4; ++q)
        LF[col*133 + lr + q] = acc[fr][fc][q];
    }
  }
  __syncthreads();
  float* brp = (blockIdx.y < 6) ? brpA + (size_t)blockIdx.y*200000
             : (blockIdx.y == 6) ? brpC : brpD;
  for (int o = t; o < OD*128; o += 256){
    int col = o >> 7, row = o & 127;
    int gr = i0 + row;
    if (gr < VV) brp[(size_t)col*VV + gr] = LF[col*133 + row];
  }
}

// ============ K5r: br = sum of 8 partial slices (6 in Xb + Rn-slice + br-slice) ============
__global__ __launch_bounds__(256) void k5r_red(const float* __restrict__ brpA,
    const float* __restrict__ brpC, const float* __restrict__ brpD,
    float* __restrict__ br){
  int idx = blockIdx.x*256 + threadIdx.x;   // float4 index, 50000 total
  if (idx >= 50000) return;
  const float4* a = (const float4*)brpA;
  float4 s = a[idx];
  #pragma unroll
  for (int sl = 1; sl < 6; ++sl){
    float4 v = a[(size_t)sl*50000 + idx];
    s.x += v.x; s.y += v.y; s.z += v.z; s.w += v.w;
  }
  {
    float4 v = ((const float4*)brpC)[idx];
    s.x += v.x; s.y += v.y; s.z += v.z; s.w += v.w;
  }
  {
    float4 v = ((const float4*)brpD)[idx];   // same region as br: read-before-write per idx
    s.x += v.x; s.y += v.y; s.z += v.z; s.w += v.w;
  }
  ((float4*)br)[idx] = s;
}

// ============ K6: e1pre += br @ W1^T (split-K) + ECR iters 95..99 + final (y==10) ============
__global__ __launch_bounds__(256) void k6_e1(const float* __restrict__ br,
    const float* __restrict__ W1, float* __restrict__ e1pre,
    const __half* __restrict__ Kn, const float* __restrict__ cost,
    float* __restrict__ accg, int* __restrict__ cnt, float* __restrict__ scal){
  __shared__ __align__(16) char smem[34816];
  const int t = threadIdx.x;
  if (blockIdx.y == 10){
    if (blockIdx.x < 16)
      ecr_block(blockIdx.x, 95, 5, true, Kn, cost, accg, cnt, scal, smem);
    return;
  }
  const int lane = t & 63, w = t >> 6;
  const int k = blockIdx.x*4 + w;
  const int f0 = blockIdx.y * 125;       // 10 chunks x 125 float4 = 1250
  float acc[OD];
  #pragma unroll
  for (int i = 0; i < OD; ++i) acc[i] = 0.f;
  const float4* w4p = (const float4*)(W1 + (size_t)k*VV);
  for (int f4 = f0 + lane; f4 < f0 + 125; f4 += 64){
    float4 wv = w4p[f4];
    #pragma unroll
    for (int i = 0; i < OD; ++i){
      float4 bv = ((const float4*)(br + (size_t)i*VV))[f4];
      acc[i] += bv.x*wv.x + bv.y*wv.y + bv.z*wv.z + bv.w*wv.w;
    }
  }
  #pragma unroll
  for (int i = 0; i < OD; ++i)
    #pragma unroll
    for (int off = 32; off; off >>= 1)
      acc[i] += __shfl_down(acc[i], off, 64);
  float (*red)[OD] = (float(*)[OD])smem;
  if (lane == 0){
    #pragma unroll
    for (int i = 0; i < OD; ++i) red[w][i] = acc[i];
  }
  __syncthreads();
  if (t < 160){
    int ww = t / OD, i = t - ww*OD;
    int kk = blockIdx.x*4 + ww;
    atomicAdd(&e1pre[kk*OD + i], red[ww][i]);
  }
}

// ============ K6b: in-place bias + softplus on e1 (8000 elems) ============
__global__ __launch_bounds__(256) void k6b_sp(const float* __restrict__ b1,
    float* __restrict__ e1t){
  int idx = blockIdx.x*256 + threadIdx.x;
  if (idx >= ENH*OD) return;
  int kk = idx / OD;
  float x = e1t[idx] + b1[kk];
  e1t[idx] = (x > 20.f) ? x : log1pf(__expf(x));
}

// ============ K7: e2^T = softplus(e1 @ W2^T + b2) ============
__global__ __launch_bounds__(256) void k7_e2(const float* __restrict__ e1t,
    const float* __restrict__ W2, const float* __restrict__ b2, float* __restrict__ e2t){
  const int t = threadIdx.x;
  const int lane = t & 63, w = t >> 6;
  const int k = blockIdx.x*4 + w;
  float acc[OD];
  #pragma unroll
  for (int i = 0; i < OD; ++i) acc[i] = 0.f;
  for (int j = lane; j < ENH; j += 64){
    float wv = W2[(size_t)k*ENH + j];
    #pragma unroll
    for (int i = 0; i < OD; ++i) acc[i] += e1t[j*OD + i] * wv;
  }
  #pragma unroll
  for (int i = 0; i < OD; ++i)
    #pragma unroll
    for (int off = 32; off; off >>= 1)
      acc[i] += __shfl_down(acc[i], off, 64);
  __shared__ float red[4][OD];
  if (lane == 0){
    #pragma unroll
    for (int i = 0; i < OD; ++i) red[w][i] = acc[i];
  }
  __syncthreads();
  if (t < 160){
    int ww = t / OD, i = t - ww*OD;
    int kk = blockIdx.x*4 + ww;
    float x = red[ww][i] + b2[kk];
    float sp = (x > 20.f) ? x : log1pf(__expf(x));
    e2t[kk*OD + i] = sp;
  }
}

// ============ K8a: mu_pre/lv_pre (stored [t50][i]) ============
__global__ __launch_bounds__(256) void k8a_mulv(const float* __restrict__ e2t,
    const float* __restrict__ Wmu, const float* __restrict__ bmu,
    const float* __restrict__ Wlv, const float* __restrict__ blv,
    float* __restrict__ mupre, float* __restrict__ lvpre){
  int id = blockIdx.x*256 + threadIdx.x;
  if (id >= NTOP*OD) return;
  int t50 = id / OD, i = id - t50*OD;
  float am = 0.f, al = 0.f;
  for (int kk = 0; kk < ENH; ++kk){
    float e = e2t[kk*OD + i];
    am += e * Wmu[t50*ENH + kk];
    al += e * Wlv[t50*ENH + kk];
  }
  mupre[t50*OD + i] = am + bmu[t50];
  lvpre[t50*OD + i] = al + blv[t50];
}

// ============ K8b: BN + KL + z/theta + small SNE(50) + theta_reduced (single WG) ============
__global__ __launch_bounds__(256) void k8b_theta(const float* __restrict__ mupre,
    const float* __restrict__ lvpre,
    const float* __restrict__ g_mu, const float* __restrict__ be_mu,
    const float* __restrict__ g_lv, const float* __restrict__ be_lv,
    const float* __restrict__ eps_noise, const float* __restrict__ projK,
    float* __restrict__ thred, float* __restrict__ d_out3, float* __restrict__ scal){
  __shared__ float mu[NTOP][OD];
  __shared__ float lv[NTOP][OD];
  __shared__ float th[OD][NTOP];
  __shared__ float C2[NTOP][NTOP];
  __shared__ float P2[NTOP][NTOP];
  __shared__ float f2[NTOP], nf[NTOP];
  __shared__ float sred[4];
  __shared__ float eps2s[2];
  const int t = threadIdx.x;
  if (t < NTOP){
    float m = 0.f;
    for (int i = 0; i < OD; ++i) m += mupre[t*OD + i];
    m *= (1.f/OD);
    float v = 0.f;
    for (int i = 0; i < OD; ++i){ float d = mupre[t*OD+i] - m; v += d*d; }
    v *= (1.f/OD);
    float sc = g_mu[t] * rsqrtf(v + 1e-5f);
    float sh = be_mu[t];
    for (int i = 0; i < OD; ++i) mu[t][i] = (mupre[t*OD+i] - m)*sc + sh;
    m = 0.f;
    for (int i = 0; i < OD; ++i) m += lvpre[t*OD + i];
    m *= (1.f/OD);
    v = 0.f;
    for (int i = 0; i < OD; ++i){ float d = lvpre[t*OD+i] - m; v += d*d; }
    v *= (1.f/OD);
    sc = g_lv[t] * rsqrtf(v + 1e-5f);
    sh = be_lv[t];
    for (int i = 0; i < OD; ++i) lv[t][i] = (lvpre[t*OD+i] - m)*sc + sh;
  }
  __syncthreads();
  { // KL divergence
    float kl = 0.f;
    if (t < OD){
      const float var2 = 1.f - 1.f/(float)NTOP;
      const float lv2 = logf(var2);
      float ssum = 0.f;
      for (int q = 0; q < NTOP; ++q){
        float l = lv[q][t];
        float m = mu[q][t];
        ssum += (__expf(l) + m*m)/var2 + lv2 - l;
      }
      kl = 0.5f*(ssum - (float)NTOP);
    }
    #pragma unroll
    for (int off = 32; off; off >>= 1) kl += __shfl_down(kl, off, 64);
    if ((t & 63) == 0) sred[t >> 6] = kl;
    __syncthreads();
    if (t == 0) scal[2] = (sred[0]+sred[1]+sred[2]+sred[3]) * (1.f/OD);
    __syncthreads();
  }
  if (t < OD){ // z + softmax
    float z[NTOP];
    float mx = -1e30f;
    for (int q = 0; q < NTOP; ++q){
      float val = mu[q][t] + eps_noise[t*NTOP + q]*__expf(0.5f*lv[q][t]);
      z[q] = val;
      mx = fmaxf(mx, val);
    }
    float ssum = 0.f;
    for (int q = 0; q < NTOP; ++q){ float e = __expf(z[q]-mx); z[q] = e; ssum += e; }
    float inv = 1.f/ssum;
    for (int q = 0; q < NTOP; ++q) th[t][q] = z[q]*inv;
  }
  __syncthreads();
  { // C2 + mean
    float csum = 0.f;
    for (int pr = t; pr < NTOP*NTOP; pr += 256){
      int a = pr / NTOP, b = pr - (pr/NTOP)*NTOP;
      float ss = 0.f;
      for (int i = 0; i < OD; ++i){ float d = th[i][a] - th[i][b]; ss += d*d; }
      C2[a][b] = ss;
      csum += ss;
    }
    #pragma unroll
    for (int off = 32; off; off >>= 1) csum += __shfl_down(csum, off, 64);
    if ((t & 63) == 0) sred[t >> 6] = csum;
    __syncthreads();
    if (t == 0){
      float meanC = (sred[0]+sred[1]+sred[2]+sred[3]) / ((float)NTOP*NTOP);
      float e2 = meanC / logf(30.f) + 1e-6f;
      eps2s[0] = e2; eps2s[1] = 1.f/e2;
    }
  }
  if (t < NTOP) f2[t] = 0.f;
  __syncthreads();
  const float loga2 = -logf((float)NTOP);
  for (int it = 0; it < 20; ++it){
    if (t < NTOP){
      float ie = eps2s[1];
      float ssum = 0.f;
      for (int sI = 0; sI < NTOP; ++sI)
        ssum += __expf((f2[sI] - C2[t][sI]) * ie);
      float lse = __logf(ssum);
      nf[t] = 0.5f*(f2[t] + eps2s[0]*(loga2 - lse));
    }
    __syncthreads();
    if (t < NTOP) f2[t] = nf[t];
    __syncthreads();
  }
  for (int pr = t; pr < NTOP*NTOP; pr += 256){
    int a = pr / NTOP, b = pr - (pr/NTOP)*NTOP;
    P2[a][b] = __expf((f2[a] + f2[b] - C2[a][b]) * eps2s[1]);
  }
  __syncthreads();
  for (int o = t; o < NTOP*OD; o += 256){
    int t50 = o / OD, kk = o - (o/OD)*OD;
    float ssum = 0.f;
    for (int sI = 0; sI < NTOP; ++sI)
      ssum += P2[t50][sI] * projK[sI*OD + kk];
    thred[kk*NTOP + t50] = ssum;
    d_out3[kk*NTOP + t50] = ssum;
  }
}

// ============ K10: cost, beta=softmax(-5c over topics), Kn=(exp(-5(c-cmin)))^4 fp16 ============
__global__ __launch_bounds__(256) void k10_cost(const float* __restrict__ temb,
    const float* __restrict__ wemb, float* __restrict__ cost, __half* __restrict__ Kn,
    float* __restrict__ beta){
  __shared__ float Tt[100][52];
  __shared__ float wed[100][68];
  __shared__ float sc[52][64];
  __shared__ float tn[52];
  __shared__ float wn[64];
  const int t = threadIdx.x;
  const int j0 = blockIdx.x * 64;
  const int tg = t >> 4, jg = t & 15;
  float am[4][4];
  #pragma unroll
  for (int a = 0; a < 4; ++a)
    #pragma unroll
    for (int b = 0; b < 4; ++b) am[a][b] = 0.f;
  float tnp = 0.f, wnp = 0.f;
  for (int c = 0; c < 2; ++c){
    __syncthreads();
    const int dbase = c*100;
    for (int idx = t; idx < NTOP*100; idx += 256){
      int t50 = idx / 100, d = idx - t50*100;
      Tt[d][t50] = temb[t50*NEMB + dbase + d];
    }
    for (int idx = t; idx < 64*100; idx += 256){
      int j = idx / 100, d = idx - j*100;
      int gj = j0 + j;
      wed[d][j] = (gj < VV) ? wemb[(size_t)gj*NEMB + dbase + d] : 0.f;
    }
    __syncthreads();
    if (t < NTOP){
      float a = 0.f;
      for (int d = 0; d < 100; ++d){ float v = Tt[d][t]; a += v*v; }
      tnp += a;
    }
    if (t >= 64 && t < 128){
      int j = t - 64;
      float a = 0.f;
      for (int d = 0; d < 100; ++d){ float v = wed[d][j]; a += v*v; }
      wnp += a;
    }
    if (t < 208){
      for (int d = 0; d < 100; ++d){
        const float4 tv = *(const float4*)(&Tt[d][tg*4]);
        const float4 wv = *(const float4*)(&wed[d][jg*4]);
        am[0][0] += tv.x*wv.x; am[0][1] += tv.x*wv.y; am[0][2] += tv.x*wv.z; am[0][3] += tv.x*wv.w;
        am[1][0] += tv.y*wv.x; am[1][1] += tv.y*wv.y; am[1][2] += tv.y*wv.z; am[1][3] += tv.y*wv.w;
        am[2][0] += tv.z*wv.x; am[2][1] += tv.z*wv.y; am[2][2] += tv.z*wv.z; am[2][3] += tv.z*wv.w;
        am[3][0] += tv.w*wv.x; am[3][1] += tv.w*wv.y; am[3][2] += tv.w*wv.z; am[3][3] += tv.w*wv.w;
      }
    }
  }
  if (t < NTOP) tn[t] = tnp;
  if (t >= 64 && t < 128) wn[t-64] = wnp;
  __syncthreads();
  if (t < 208){
    #pragma unroll
    for (int a = 0; a < 4; ++a){
      int t50 = tg*4 + a;
      if (t50 < NTOP){
        float tv = tn[t50];
        float cc[4];
        #pragma unroll
        for (int b = 0; b < 4; ++b) cc[b] = tv + wn[jg*4+b] - 2.f*am[a][b];
        int gj = j0 + jg*4;
        if (gj + 3 < VV)
          *(float4*)(cost + (size_t)t50*VV + gj) = make_float4(cc[0],cc[1],cc[2],cc[3]);
        #pragma unroll
        for (int b = 0; b < 4; ++b) sc[t50][jg*4+b] = -5.f*cc[b];
      }
    }
  }
  __syncthreads();
  if (t < 64){
    int gj = j0 + t;
    if (gj < VV){
      float mx = -1e30f;
      for (int q = 0; q < NTOP; ++q) mx = fmaxf(mx, sc[q][t]);
      float ssum = 0.f;
      for (int q = 0; q < NTOP; ++q){ float e = __expf(sc[q][t]-mx); sc[q][t] = e; ssum += e; }
      float inv = 1.f/ssum;
      for (int q = 0; q < NTOP; ++q){
        float e = sc[q][t];
        float e2 = e*e;
        Kn[(size_t)q*KNS + gj] = __float2half(e2*e2);   // exp(-20(c-cmin))
        beta[(size_t)q*VV + gj] = e*inv;
      }
    }
  }
}

// ============ K12: R = theta_red @ beta, column BN ============
__global__ __launch_bounds__(256) void k12_reconA(const float* __restrict__ thred,
    const float* __restrict__ beta, const float* __restrict__ g_dec,
    const float* __restrict__ be_dec, float* __restrict__ Rn){
  __shared__ float trs[OD][NTOP];
  const int t = threadIdx.x;
  for (int o = t; o < OD*NTOP; o += 256) trs[o/NTOP][o - (o/NTOP)*NTOP] = thred[o];
  __syncthreads();
  int j = blockIdx.x*256 + t;
  if (j >= VV) return;
  float a[OD];
  #pragma unroll
  for (int i = 0; i < OD; ++i) a[i] = 0.f;
  for (int q = 0; q < NTOP; ++q){
    float bv = beta[(size_t)q*VV + j];
    #pragma unroll
    for (int i = 0; i < OD; ++i) a[i] += trs[i][q]*bv;
  }
  float m = 0.f;
  #pragma unroll
  for (int i = 0; i < OD; ++i) m += a[i];
  m *= (1.f/OD);
  float v = 0.f;
  #pragma unroll
  for (int i = 0; i < OD; ++i){ float d = a[i]-m; v += d*d; }
  v *= (1.f/OD);
  float scale = g_dec[j]*rsqrtf(v + 1e-5f);
  float sh = be_dec[j];
  #pragma unroll
  for (int i = 0; i < OD; ++i) Rn[(size_t)i*VV + j] = (a[i]-m)*scale + sh;
}

// ============ K13: per-row sums for softmax + cross-entropy ============
__global__ __launch_bounds__(256) void k13_reconB(const float* __restrict__ Rn,
    const float* __restrict__ br, float* __restrict__ rows){
  const int i = blockIdx.x;
  const int t = threadIdx.x;
  float s1 = 0.f, s2 = 0.f, s3 = 0.f;
  for (int j = t; j < VV; j += 256){
    float rn = Rn[(size_t)i*VV + j];
    float bv = br[(size_t)i*VV + j];
    s1 += __expf(rn);
    s2 += bv*rn;
    s3 += bv;
  }
  #pragma unroll
  for (int off = 32; off; off >>= 1){
    s1 += __shfl_down(s1, off, 64);
    s2 += __shfl_down(s2, off, 64);
    s3 += __shfl_down(s3, off, 64);
  }
  __shared__ float red[3][4];
  int lane = t & 63, w = t >> 6;
  if (lane == 0){ red[0][w] = s1; red[1][w] = s2; red[2][w] = s3; }
  __syncthreads();
  if (t == 0){
    rows[i]      = red[0][0]+red[0][1]+red[0][2]+red[0][3];
    rows[40 + i] = red[1][0]+red[1][1]+red[1][2]+red[1][3];
    rows[80 + i] = red[2][0]+red[2][1]+red[2][2]+red[2][3];
  }
}

// ============ K14: final losses ============
__global__ void k14_final(const float* __restrict__ rows, const float* __restrict__ scal,
    float* __restrict__ out){
  const int t = threadIdx.x;
  float v = 0.f;
  if (t < OD) v = rows[40 + t] - logf(rows[t]) * rows[80 + t];
  #pragma unroll
  for (int off = 32; off; off >>= 1) v += __shfl_down(v, off, 64);
  if (t == 0){
    float recon = -v * (1.f/OD);
    float tm = recon + scal[2];
    float ecr = 250.f * scal[3];
    out[0] = tm + ecr;
    out[1] = tm;
    out[2] = ecr;
  }
}

extern "C" void kernel_launch(void* const* d_in, const int* in_sizes, int n_in,
                              void* d_out, int out_size, void* d_ws, size_t ws_size,
                              hipStream_t stream){
  const float* bow   = (const float*)d_in[0];
  const float* epsn  = (const float*)d_in[1];
  const float* W1    = (const float*)d_in[2];
  const float* b1    = (const float*)d_in[3];
  const float* W2    = (const float*)d_in[4];
  const float* b2    = (const float*)d_in[5];
  const float* Wmu   = (const float*)d_in[6];
  const float* bmu   = (const float*)d_in[7];
  const float* Wlv   = (const float*)d_in[8];
  const float* blv   = (const float*)d_in[9];
  const float* g_mu  = (const float*)d_in[10];
  const float* be_mu = (const float*)d_in[11];
  const float* g_lv  = (const float*)d_in[12];
  const float* be_lv = (const float*)d_in[13];
  const float* g_dec = (const float*)d_in[14];
  const float* be_dec= (const float*)d_in[15];
  const float* wemb  = (const float*)d_in[16];
  const float* temb  = (const float*)d_in[17];
  const float* projV = (const float*)d_in[18];
  const float* projK = (const float*)d_in[19];
  char* ws = (char*)d_ws;
  float* r     = (float*)(ws + OFF_R);
  float* s     = (float*)(ws + OFF_S);
  float* scal  = (float*)(ws + OFF_SCAL);
  float* phiA  = (float*)(ws + OFF_PHIA);
  float* phiB  = (float*)(ws + OFF_PHIB);
  float* rows  = (float*)(ws + OFF_ROWS);
  float* accg  = (float*)(ws + OFF_PARTS);
  int*   cnt   = (int*)(ws + OFF_FLAGS);
  float* mupre = (float*)(ws + OFF_MUPRE);
  float* lvpre = (float*)(ws + OFF_LVPRE);
  float* e1t   = (float*)(ws + OFF_E1T);
  float* e2t   = (float*)(ws + OFF_E2T);
  float* thred = (float*)(ws + OFF_THRED);
  float* br    = (float*)(ws + OFF_BOWRED);
  __hip_bfloat16* pvt = (__hip_bfloat16*)(ws + OFF_PVT);
  __hip_bfloat16* Xb  = (__hip_bfloat16*)(ws + OFF_XB);
  __half* Ce   = (__half*)(ws + OFF_CE);
  float* cost  = (float*)(ws + OFF_COST);
  __half* Kn   = (__half*)(ws + OFF_KM);
  float* beta  = (float*)(ws + OFF_BETA);
  float* Rn    = (float*)(ws + OFF_RN);
  float* sbuf0 = (float*)(ws + OFF_RN);              // sweep rowsum tri-buffer
  float* sbuf1 = (float*)(ws + OFF_RN + 20224);
  float* sbuf2 = (float*)(ws + OFF_RN + 40448);
  float* sbuf[3] = {sbuf0, sbuf1, sbuf2};
  float* P2b[2] = {phiA, phiB};                      // phi^(k) in P2b[k&1]
  float* brpA  = (float*)(ws + OFF_XB);      // 6 slices, Xb dead after k3
  float* brpC  = (float*)(ws + OFF_RN);      // slice 6: Rn region (sbuf dead by k5)
  float* brpD  = (float*)(ws + OFF_BOWRED);  // slice 7: br region (k5r read-then-write)
  float* out   = (float*)d_out;

  hipMemsetAsync(d_ws, 0, ZERO_BYTES, stream);
  hipMemsetAsync(ws + OFF_RN, 0, 60672, stream);   // sweep rowsum tri-buffer
  // ECR prerequisites first (inputs only), so ECR blocks can ride everything after.
  k10_cost<<<79, 256, 0, stream>>>(temb, wemb, cost, Kn, beta);
  // ECR iters 0..9 ride k1 (16 blocks at x=40,41).
  k1_stats<<<dim3(42, 8), 256, 0, stream>>>(bow, Xb, r, s, Kn, cost, accg, cnt, scal);
  k2_eps<<<1, 256, 0, stream>>>(r, s, scal);
  // ECR iters 10..34 ride the SYRK Ce GEMM (820 upper-triangle tiles, no mirror).
  k3_gemm_ecr<<<836, 256, 0, stream>>>(Xb, r, scal, Ce, Kn, cost, accg, cnt);
  // 20 symmetric sweeps (upper-triangle Ce, deferred phi); ECR 35..74 (2 per launch).
  for (int g = 0; g < 20; ++g){
    k4_symsweep<<<836, 256, 0, stream>>>(Ce,
        P2b[(g+1)&1] /* phi^(g-1); unused at g=0 */, P2b[g&1] /* phi^(g) out */,
        sbuf[g%3], sbuf[(g+1)%3], sbuf[(g+2)%3],
        Kn, cost, accg, cnt, scal, 35 + 2*g, g);
  }
  // blocks 0..19: phi^(20) from (phi^(19)=phiB, ssum^(19)=sbuf[2]) -> phiA; rest: pvt.
  k5p_pvt<<<980, 256, 0, stream>>>(projV, pvt, phiB, sbuf[2], phiA);
  // ECR iters 75..94 ride k5 (16 blocks at x=40,41).
  k5_bowred<<<dim3(42, 8), 256, 0, stream>>>(Ce, phiA, pvt, brpA, brpC, brpD,
                                             Kn, cost, accg, cnt, scal);
  k5r_red<<<196, 256, 0, stream>>>(brpA, brpC, brpD, br);
  // ECR iters 95..99 + final dot ride k6 (y==10 row).
  k6_e1<<<dim3(50, 11), 256, 0, stream>>>(br, W1, e1t, Kn, cost, accg, cnt, scal);
  k6b_sp<<<32, 256, 0, stream>>>(b1, e1t);
  k7_e2<<<50, 256, 0, stream>>>(e1t, W2, b2, e2t);
  k8a_mulv<<<8, 256, 0, stream>>>(e2t, Wmu, bmu, Wlv, blv, mupre, lvpre);
  k8b_theta<<<1, 256, 0, stream>>>(mupre, lvpre, g_mu, be_mu, g_lv, be_lv,
                                   epsn, projK, thred, out + 3, scal);
  k12_reconA<<<20, 256, 0, stream>>>(thred, beta, g_dec, be_dec, Rn);
  k13_reconB<<<40, 256, 0, stream>>>(Rn, br, rows);
  k14_final<<<1, 64, 0, stream>>>(rows, scal, out);
}

// Round 16
// 753.866 us; speedup vs baseline: 1.0174x; 1.0174x over previous
//
#include <hip/hip_runtime.h>
#include <hip/hip_bf16.h>
#include <hip/hip_fp16.h>

#define VV 5000
#define NTOP 50
#define ENH 200
#define NEMB 200
#define OD 40
#define MP 5120
#define KNS 5008   // padded row stride (halfs) for scaled fp16 kernel matrix Kn

typedef __attribute__((ext_vector_type(8))) short short8;
typedef __attribute__((ext_vector_type(4))) float f32x4;

// ---------------- workspace layout (bytes) ----------------
constexpr size_t OFF_R      = 0;          // 5000 f (atomic accum, zeroed)
constexpr size_t OFF_S      = 20224;      // 512 f (atomic accum, zeroed)
constexpr size_t OFF_SCAL   = 22528;      // 64 f: [0]=eps [1]=1/eps [2]=loss_KL [3]=ecr_dot
constexpr size_t OFF_PHIA   = 22784;      // 5000 f (zeroed = phi^(0)); phi ping
constexpr size_t OFF_PHIB   = 43008;      // 5000 f; phi pong
constexpr size_t OFF_ROWS   = 63232;      // S1[40] S2[40] S3[40]
constexpr size_t OFF_PARTS  = 63744;      // ECR acc: 3 buffers x 64 f (tri-buffered, zeroed)
constexpr size_t OFF_FLAGS  = 71936;      // ECR counter: 1 int, monotone (zeroed)
constexpr size_t OFF_MUPRE  = 72960;      // 50*40 f
constexpr size_t OFF_LVPRE  = 81152;
constexpr size_t OFF_E1T    = 89344;      // 200*40 f  [k][i] (atomic accum, zeroed)
constexpr size_t OFF_E2T    = 121600;
constexpr size_t OFF_THRED  = 153856;     // 40*50 f
constexpr size_t OFF_BOWRED = 162048;     // 40*5000 f: brp slice 7 during k5; br after k5r
constexpr size_t ZERO_BYTES = 962304;     // everything below PVT is zeroed each call
constexpr size_t OFF_PVT    = 962304;     // 48*5120 bf16 (proj_V transposed, padded)
constexpr size_t OFF_XB     = 1453824;    // 5120*512 bf16 (bow.T); dead after k3 -> brp slices 0..5
constexpr size_t OFF_CE     = 6696704;    // 5000*5000 fp16 (C/eps), UPPER TRIANGLE (128-blocks) only
constexpr size_t OFF_COST   = 56696832;   // 50*5000 f; alive until ECR final (k6)
constexpr size_t OFF_KM     = 57697024;   // Kn: 50*5008 fp16 (column-max-scaled exp(-20c))
constexpr size_t OFF_BETA   = 58697216;
constexpr size_t OFF_RN     = 59697408;   // sbuf[3] during sweeps; brpC in k5; Rn after k12
// sweep row-sum tri-buffer: 3 x 5056 f at byte stride 20224 (zeroed by extra memset)

// ============ ECR block: n_iters Sinkhorn iterations, resumable across launches ============
// The PROVEN 16-block/LLC protocol. Cost model: ~1.5-1.8us/iter hidden, ~3.4us/iter
// ECR-bound. R16 rebalance (k3 went ECR-bound after SYRK halved its window):
// k1 10, k3 12, k4x20 3 each, k5 13, k6 5+final = 100.
__device__ __forceinline__ void ecr_block(int b, int it_base, int n_iters, bool do_final,
    const __half* __restrict__ Kn, const float* __restrict__ cost,
    float* __restrict__ acc, int* __restrict__ cnt, float* __restrict__ scal,
    char* smem){
  __half* KmL = (__half*)smem;                 // 50*322 halfs (stride 322 -> conflict-free)
  float* varr = (float*)(smem + 32208);        // 320 f, 16B aligned
  float* us   = (float*)(smem + 33488);        // 52 f
  float* p5   = (float*)(smem + 33696);        // 5*52 f
  float* redr = (float*)(smem + 34736);        // 4 f
  const int t = threadIdx.x;
  const int base = (b < 8) ? b*313 : 2504 + (b-8)*312;
  const int sz   = (b < 8) ? 313 : 312;
  for (int c = t; c < 322; c += 256){
    if (c < sz){
      #pragma unroll
      for (int q = 0; q < NTOP; ++q)
        KmL[q*322 + c] = Kn[(size_t)q*KNS + base + c];
    } else {
      #pragma unroll
      for (int q = 0; q < NTOP; ++q) KmL[q*322 + c] = __float2half(0.f);
    }
  }
  if (t < 52){
    float u0 = 0.f;
    if (t < NTOP){
      if (it_base == 0) u0 = 1.f/(float)NTOP;
      else {
        float sm = __hip_atomic_load(&acc[((it_base-1)%3)*64 + t],
                                     __ATOMIC_RELAXED, __HIP_MEMORY_SCOPE_AGENT);
        u0 = (1.f/(float)NTOP)/(sm + 1e-16f);
      }
    }
    us[t] = u0;
  }
  for (int c = sz + t; c < 320; c += 256) varr[c] = 0.f;
  __syncthreads();
  const bool act = (2*t < sz);
  for (int k = 0; k < n_iters; ++k){
    const int g = it_base + k;
    if (act){
      float w0 = 0.f, w1 = 0.f, w2 = 0.f, w3 = 0.f;
      #pragma unroll
      for (int q = 0; q < NTOP; q += 2){
        float u0 = us[q], u1 = us[q+1];
        float2 f0 = __half22float2(*(const __half2*)(KmL + q*322 + 2*t));
        float2 f1 = __half22float2(*(const __half2*)(KmL + (q+1)*322 + 2*t));
        w0 += f0.x*u0; w1 += f0.y*u0;
        w2 += f1.x*u1; w3 += f1.y*u1;
      }
      float2 vv;
      vv.x = (1.f/(float)VV)/((w0+w2) + 1e-16f);
      vv.y = (2*t+1 < sz) ? (1.f/(float)VV)/((w1+w3) + 1e-16f) : 0.f;
      *(float2*)(varr + 2*t) = vv;
    }
    __syncthreads();
    if (t < 250){
      const int qq = t % NTOP, stripe = t / NTOP;
      const __half* kp = KmL + qq*322 + stripe*64;
      const float* vp = varr + stripe*64;
      float s0 = 0.f, s1 = 0.f, s2 = 0.f, s3 = 0.f;
      #pragma unroll
      for (int n = 0; n < 64; n += 4){
        float2 fa = __half22float2(*(const __half2*)(kp + n));
        float2 fb = __half22float2(*(const __half2*)(kp + n + 2));
        float4 v4 = *(const float4*)(vp + n);
        s0 += fa.x*v4.x; s1 += fa.y*v4.y; s2 += fb.x*v4.z; s3 += fb.y*v4.w;
      }
      p5[stripe*52 + qq] = (s0+s1)+(s2+s3);
    }
    __syncthreads();
    if (t < NTOP){
      float sm = p5[t] + p5[52+t] + p5[104+t] + p5[156+t] + p5[208+t];
      __hip_atomic_fetch_add(&acc[(g%3)*64 + t], sm,
                             __ATOMIC_RELAXED, __HIP_MEMORY_SCOPE_AGENT);
    }
    __asm__ volatile("s_waitcnt vmcnt(0)" ::: "memory");
    if (t == 0){
      __hip_atomic_fetch_add(cnt, 1, __ATOMIC_RELEASE, __HIP_MEMORY_SCOPE_AGENT);
      const int tgt = 16*(g+1);
      while (__hip_atomic_load(cnt, __ATOMIC_ACQUIRE, __HIP_MEMORY_SCOPE_AGENT) < tgt)
        __builtin_amdgcn_s_sleep(1);
    }
    if (t < NTOP){
      float sm = __hip_atomic_load(&acc[(g%3)*64 + t],
                                   __ATOMIC_RELAXED, __HIP_MEMORY_SCOPE_AGENT);
      us[t] = (1.f/(float)NTOP)/(sm + 1e-16f);
    }
    if (t < 64)
      __hip_atomic_store(&acc[((g+2)%3)*64 + t], 0.f,
                         __ATOMIC_RELAXED, __HIP_MEMORY_SCOPE_AGENT);
    __syncthreads();
  }
  if (!do_final) return;
  float lsum = 0.f;
  if (act){
    float w0 = 0.f, w1 = 0.f, w2 = 0.f, w3 = 0.f;
    #pragma unroll
    for (int q = 0; q < NTOP; q += 2){
      float u0 = us[q], u1 = us[q+1];
      float2 f0 = __half22float2(*(const __half2*)(KmL + q*322 + 2*t));
      float2 f1 = __half22float2(*(const __half2*)(KmL + (q+1)*322 + 2*t));
      w0 += f0.x*u0; w1 += f0.y*u0;
      w2 += f1.x*u1; w3 += f1.y*u1;
    }
    float v0 = (1.f/(float)VV)/((w0+w2) + 1e-16f);
    const bool ok1 = (2*t+1 < sz);
    float v1 = ok1 ? (1.f/(float)VV)/((w1+w3) + 1e-16f) : 0.f;
    float accv = 0.f;
    #pragma unroll
    for (int q = 0; q < NTOP; ++q){
      float2 f = __half22float2(*(const __half2*)(KmL + q*322 + 2*t));
      float uq = us[q];
      float c0 = cost[(size_t)q*VV + base + 2*t];
      accv += uq*f.x*v0*c0;
      if (ok1){
        float c1 = cost[(size_t)q*VV + base + 2*t + 1];
        accv += uq*f.y*v1*c1;
      }
    }
    lsum = accv;
  }
  #pragma unroll
  for (int off = 32; off; off >>= 1) lsum += __shfl_down(lsum, off, 64);
  if ((t & 63) == 0) redr[t >> 6] = lsum;
  __syncthreads();
  if (t == 0) atomicAdd(&scal[3], redr[0]+redr[1]+redr[2]+redr[3]);
}

// ============ K1: transpose bow + stats; x>=40 hosts ECR iters 0..9 (16 blocks) ============
__global__ __launch_bounds__(256) void k1_stats(const float* __restrict__ bow,
    __hip_bfloat16* __restrict__ Xb, float* __restrict__ r, float* __restrict__ s,
    const __half* __restrict__ Kn, const float* __restrict__ cost,
    float* __restrict__ accg, int* __restrict__ cnt, float* __restrict__ scal){
  __shared__ __align__(16) char smem[34816];
  const int t = threadIdx.x;
  if (blockIdx.x >= 40){
    int b = (blockIdx.x - 40)*8 + blockIdx.y;
    ecr_block(b, 0, 10, false, Kn, cost, accg, cnt, scal, smem);
    return;
  }
  float (*lds)[129] = (float(*)[129])smem;   // 64*129*4 = 33024 <= 34816
  const int i0 = blockIdx.x * 128, d0 = blockIdx.y * 64;
  #pragma unroll
  for (int m = 0; m < 32; ++m){
    int idx = m*256 + t;
    int di = idx >> 7;
    int ii = idx & 127;
    int gi = i0 + ii;
    lds[di][ii] = (gi < VV) ? bow[(size_t)(d0+di)*VV + gi] : 0.f;
  }
  __syncthreads();
  if (t < 128 && (i0 + t) < VV){
    float acc = 0.f;
    for (int di = 0; di < 64; ++di){ float v = lds[di][t]; acc += v*v; }
    atomicAdd(&r[i0+t], acc);
  }
  if (t < 64){
    float acc = 0.f;
    for (int ii = 0; ii < 128; ++ii) acc += lds[t][ii];
    atomicAdd(&s[d0+t], acc);
  }
  __syncthreads();
  #pragma unroll
  for (int m = 0; m < 32; ++m){
    int idx = m*256 + t;
    int ii = idx >> 6;
    int dd = idx & 63;
    Xb[(size_t)(i0+ii)*512 + d0 + dd] = __float2bfloat16(lds[dd][ii]);
  }
}

// ============ K2: eps from closed-form mean(C) ============
__global__ __launch_bounds__(256) void k2_eps(const float* __restrict__ r,
    const float* __restrict__ s, float* __restrict__ scal){
  const int t = threadIdx.x;
  float a = 0.f, b = 0.f;
  for (int i = t; i < VV; i += 256) a += r[i];
  for (int d = t; d < 512; d += 256){ float v = s[d]; b += v*v; }
  #pragma unroll
  for (int off = 32; off; off >>= 1){
    a += __shfl_down(a, off, 64);
    b += __shfl_down(b, off, 64);
  }
  __shared__ float ra[4], rb[4];
  int lane = t & 63, w = t >> 6;
  if (lane == 0){ ra[w] = a; rb[w] = b; }
  __syncthreads();
  if (t == 0){
    float sa = ra[0]+ra[1]+ra[2]+ra[3];
    float sb = rb[0]+rb[1]+rb[2]+rb[3];
    float meanC = 2.f*sa/(float)VV - 2.f*sb/((float)VV*(float)VV);
    float eps = meanC / logf(30.f) + 1e-6f;
    scal[0] = eps;
    scal[1] = 1.f/eps;
  }
}

// ============ K3syrk: Ce GEMM, UPPER-TRIANGLE 128-blocks ONLY (820 tiles) + ECR 10..21 ============
__global__ __launch_bounds__(256) void k3_gemm_ecr(const __hip_bfloat16* __restrict__ Xb,
    const float* __restrict__ r, float* __restrict__ scal, __half* __restrict__ Ce,
    const __half* __restrict__ Kn, const float* __restrict__ cost,
    float* __restrict__ accg, int* __restrict__ cnt){
  __shared__ __align__(16) char smem[36864];
  if (blockIdx.x < 16){
    ecr_block(blockIdx.x, 10, 12, false, Kn, cost, accg, cnt, scal, smem);
    return;
  }
  __hip_bfloat16* As = (__hip_bfloat16*)smem;          // 128*72
  __hip_bfloat16* Bs = (__hip_bfloat16*)(smem + 128*72*2);
  const int t = threadIdx.x;
  int bt = blockIdx.x - 16;                 // 0..819 upper-triangle tiles
  int bi = 0, rem = bt;
  while (rem >= 40 - bi){ rem -= 40 - bi; ++bi; }
  const int bj = bi + rem;
  const int i0 = bi*128, j0 = bj*128;
  const int lane = t & 63, w = t >> 6;
  const int wr = w >> 1, wc = w & 1;
  const int m16 = lane & 15, q4 = lane >> 4;
  f32x4 acc[4][4];
  #pragma unroll
  for (int a = 0; a < 4; ++a)
    #pragma unroll
    for (int b = 0; b < 4; ++b) acc[a][b] = (f32x4){0.f,0.f,0.f,0.f};
  const int srow = t >> 3, sseg = t & 7;
  for (int kc = 0; kc < 512; kc += 64){
    __syncthreads();
    #pragma unroll
    for (int m = 0; m < 4; ++m){
      int row = m*32 + srow;
      uint4 va = *(const uint4*)(Xb + (size_t)(i0+row)*512 + kc + sseg*8);
      *(uint4*)(As + row*72 + sseg*8) = va;
      uint4 vb = *(const uint4*)(Xb + (size_t)(j0+row)*512 + kc + sseg*8);
      *(uint4*)(Bs + row*72 + sseg*8) = vb;
    }
    __syncthreads();
    #pragma unroll
    for (int ks = 0; ks < 64; ks += 32){
      short8 af[4], bf[4];
      #pragma unroll
      for (int f = 0; f < 4; ++f){
        af[f] = *(const short8*)(As + (wr*64 + f*16 + m16)*72 + ks + q4*8);
        bf[f] = *(const short8*)(Bs + (wc*64 + f*16 + m16)*72 + ks + q4*8);
      }
      #pragma unroll
      for (int fr = 0; fr < 4; ++fr)
        #pragma unroll
        for (int fc = 0; fc < 4; ++fc)
          acc[fr][fc] = __builtin_amdgcn_mfma_f32_16x16x32_bf16(af[fr], bf[fc], acc[fr][fc], 0, 0, 0);
    }
  }
  const float inv_eps = scal[1];
  #pragma unroll
  for (int fr = 0; fr < 4; ++fr){
    int rbase = i0 + wr*64 + fr*16 + q4*4;
    #pragma unroll
    for (int fc = 0; fc < 4; ++fc){
      int col = j0 + wc*64 + fc*16 + m16;
      if (col < VV){
        float rc = r[col];
        #pragma unroll
        for (int q = 0; q < 4; ++q){
          int row = rbase + q;
          if (row < VV){
            float val = (r[row] + rc - 2.f*acc[fr][fc][q]) * inv_eps;
            Ce[(size_t)row*VV + col] = __float2half(val);
          }
        }
      }
    }
  }
}

// ============ K4sym: one sweep over the UPPER TRIANGLE of Ce (26 MB not 50) ============
__global__ __launch_bounds__(256) void k4_symsweep(const __half* __restrict__ Ce,
    const float* __restrict__ phi_prev, float* __restrict__ phi_cur,
    const float* __restrict__ ssum_prev, float* __restrict__ ssum_next,
    float* __restrict__ ssum_zero,
    const __half* __restrict__ Kn, const float* __restrict__ cost,
    float* __restrict__ accg, int* __restrict__ cnt, float* __restrict__ scal,
    int it_base, int g){
  __shared__ __align__(16) char smem[34816];
  const int t = threadIdx.x;
  if (blockIdx.x < 16){
    ecr_block(blockIdx.x, it_base, 3, false, Kn, cost, accg, cnt, scal, smem);
    return;
  }
  const float loga = -8.517193191416238f;   // -log(5000)
  int bt = blockIdx.x - 16;                 // 0..819 upper-triangle tiles
  int bi = 0, rem = bt;
  while (rem >= 40 - bi){ rem -= 40 - bi; ++bi; }
  const int bj = bi + rem;
  const bool diag = (bi == bj);
  const int i0 = bi*128, j0 = bj*128;
  float* phiI = (float*)smem;               // 128
  float* phiJ = (float*)smem + 128;         // 128
  float* RL   = (float*)smem + 256;         // 128*17
  if (t < 128){
    int gi = i0 + t;
    float ph = 0.f;
    if (gi < VV && g > 0)
      ph = 0.5f*(phi_prev[gi] + loga - __logf(ssum_prev[gi]));
    phiI[t] = ph;
    if (diag && gi < VV){
      phi_cur[gi] = ph;
      ssum_zero[gi] = 0.f;
    }
  } else {
    int gj = j0 + (t - 128);
    float ph = 0.f;
    if (gj < VV && g > 0)
      ph = 0.5f*(phi_prev[gj] + loga - __logf(ssum_prev[gj]));
    phiJ[t-128] = ph;
  }
  __syncthreads();
  const int rg = t >> 4, cg = t & 15;
  const int jb = j0 + cg*8;
  const bool colok = jb < VV;               // 5000 % 8 == 0 -> chunk guard exact
  float pj[8];
  #pragma unroll
  for (int e = 0; e < 8; ++e) pj[e] = phiJ[cg*8 + e];
  float rowacc[8], colacc[8];
  #pragma unroll
  for (int x = 0; x < 8; ++x){ rowacc[x] = 0.f; colacc[x] = 0.f; }
  #pragma unroll
  for (int rr = 0; rr < 8; ++rr){
    int rloc = rg*8 + rr;
    int gi = i0 + rloc;
    if (gi < VV && colok){
      uint4 v = *(const uint4*)(Ce + (size_t)gi*VV + jb);
      const __half2* hp = (const __half2*)&v;
      float pI = phiI[rloc];
      #pragma unroll
      for (int e = 0; e < 4; ++e){
        float2 c = __half22float2(hp[e]);
        rowacc[rr] += __expf(pj[2*e] - c.x) + __expf(pj[2*e+1] - c.y);
        if (!diag){
          colacc[2*e]   += __expf(pI - c.x);
          colacc[2*e+1] += __expf(pI - c.y);
        }
      }
    }
  }
  #pragma unroll
  for (int rr = 0; rr < 8; ++rr) RL[(rg*8+rr)*17 + cg] = rowacc[rr];
  __syncthreads();
  if (t < 128){
    float sm = 0.f;
    #pragma unroll
    for (int c2 = 0; c2 < 16; ++c2) sm += RL[t*17 + c2];
    int gi = i0 + t;
    if (gi < VV) atomicAdd(&ssum_next[gi], sm);
  }
  if (!diag){
    __syncthreads();
    #pragma unroll
    for (int cc = 0; cc < 8; ++cc) RL[(cg*8+cc)*17 + rg] = colacc[cc];
    __syncthreads();
    if (t < 128){
      float sm = 0.f;
      #pragma unroll
      for (int r2 = 0; r2 < 16; ++r2) sm += RL[t*17 + r2];
      int gj = j0 + t;
      if (gj < VV) atomicAdd(&ssum_next[gj], sm);
    }
  }
}

// ============ K5p: blocks 0..19 compute FINAL phi^(20); rest: proj_V -> pvt ============
__global__ __launch_bounds__(256) void k5p_pvt(const float* __restrict__ projV,
    __hip_bfloat16* __restrict__ pvt, const float* __restrict__ phi19,
    const float* __restrict__ ssum19, float* __restrict__ phiF){
  const int t = threadIdx.x;
  if (blockIdx.x < 20){
    if (t < 250){
      int i = blockIdx.x*250 + t;
      phiF[i] = 0.5f*(phi19[i] + (-8.517193191416238f) - __logf(ssum19[i]));
    }
    return;
  }
  int idx = (blockIdx.x - 20)*256 + t;
  if (idx >= 48*MP) return;
  int n = idx / MP, j = idx - n*MP;
  float v = (n < OD && j < VV) ? projV[(size_t)j*OD + n] : 0.f;
  pvt[idx] = __float2bfloat16(v);
}

// ============ K5: bow_reduced partials via MFMA + ECR iters 82..94 (x>=40) ============
// Upper-only Ce: lower kc-strips read the stored transpose (coalesced) and scatter
// into As transposed with per-lane element rotation (2-way LDS conflicts).
__global__ __launch_bounds__(256) void k5_bowred(const __half* __restrict__ Ce,
    const float* __restrict__ phi, const __hip_bfloat16* __restrict__ pvt,
    float* __restrict__ brpA, float* __restrict__ brpC, float* __restrict__ brpD,
    const __half* __restrict__ Kn, const float* __restrict__ cost,
    float* __restrict__ accg, int* __restrict__ cnt, float* __restrict__ scal){
  __shared__ __align__(16) char smem[34816];
  const int t = threadIdx.x;
  if (blockIdx.x >= 40){
    int b = (blockIdx.x - 40)*8 + blockIdx.y;
    ecr_block(b, 82, 13, false, Kn, cost, accg, cnt, scal, smem);
    return;
  }
  __hip_bfloat16* As = (__hip_bfloat16*)smem;            // 128*72
  __hip_bfloat16* Bs = (__hip_bfloat16*)(smem + 18432);  // 48*72
  const int i0 = blockIdx.x * 128;
  const int k0 = blockIdx.y * 640;
  const int lane = t & 63, w = t >> 6;
  const int m16 = lane & 15, q4 = lane >> 4;
  f32x4 acc[2][3];
  #pragma unroll
  for (int a = 0; a < 2; ++a)
    #pragma unroll
    for (int b = 0; b < 3; ++b) acc[a][b] = (f32x4){0.f,0.f,0.f,0.f};
  for (int kc = k0; kc < k0 + 640; kc += 64){
    __syncthreads();
    const bool lower = (kc >> 7) < (i0 >> 7);
    if (!lower){
      #pragma unroll
      for (int m = 0; m < 4; ++m){
        int g = m*256 + t;
        int row = g >> 3, cg = g & 7;
        int gi = i0 + row, j2 = kc + cg*8;
        union { __hip_bfloat16 h[8]; short8 v; } u;
        if (gi < VV && j2 < VV){
          uint4 vce = *(const uint4*)(Ce + (size_t)gi*VV + j2);
          const __half2* hp = (const __half2*)&vce;
          float pb = phi[gi];
          float4 pj0 = *(const float4*)(phi + j2);
          float4 pj1 = *(const float4*)(phi + j2 + 4);
          float pj[8] = {pj0.x,pj0.y,pj0.z,pj0.w,pj1.x,pj1.y,pj1.z,pj1.w};
          #pragma unroll
          for (int e = 0; e < 4; ++e){
            float2 ce = __half22float2(hp[e]);
            u.h[2*e]   = __float2bfloat16(__expf(pb + pj[2*e]   - ce.x));
            u.h[2*e+1] = __float2bfloat16(__expf(pb + pj[2*e+1] - ce.y));
          }
        } else {
          #pragma unroll
          for (int e = 0; e < 8; ++e) u.h[e] = __float2bfloat16(0.f);
        }
        *(short8*)(As + row*72 + cg*8) = u.v;
      }
    } else {
      // transposed staging from stored Ce[kc..kc+63][i0..i0+127]
      #pragma unroll
      for (int m = 0; m < 4; ++m){
        int g = m*256 + t;
        int sr = g >> 4;            // 0..63  (source row = j2 local)
        int lg = g & 15;
        int scb = lg * 8;           // 0..120 (source col base = gi local)
        int j2 = kc + sr;           // j2 < i0 <= 4992 -> valid stored row
        uint4 vce = *(const uint4*)(Ce + (size_t)j2*VV + i0 + scb);
        const __half* hp = (const __half*)&vce;
        float pj2 = phi[j2];
        #pragma unroll
        for (int e = 0; e < 8; ++e){
          int e2 = (e + lg) & 7;
          int gi = i0 + scb + e2;
          float p = 0.f;
          if (gi < VV)
            p = __expf(phi[gi] + pj2 - __half2float(hp[e2]));
          As[(scb + e2)*72 + sr] = __float2bfloat16(p);
        }
      }
    }
    #pragma unroll
    for (int m = 0; m < 12; ++m){
      int idx = m*256 + t;
      int row = idx >> 6, c = idx & 63;
      Bs[row*72 + c] = pvt[(size_t)row*MP + kc + c];
    }
    __syncthreads();
    #pragma unroll
    for (int ks = 0; ks < 64; ks += 32){
      short8 af[2], bf[3];
      #pragma unroll
      for (int f = 0; f < 2; ++f)
        af[f] = *(const short8*)(As + (w*32 + f*16 + m16)*72 + ks + q4*8);
      #pragma unroll
      for (int f = 0; f < 3; ++f)
        bf[f] = *(const short8*)(Bs + (f*16 + m16)*72 + ks + q4*8);
      #pragma unroll
      for (int fr = 0; fr < 2; ++fr)
        #pragma unroll
        for (int fc = 0; fc < 3; ++fc)
          acc[fr][fc] = __builtin_amdgcn_mfma_f32_16x16x32_bf16(af[fr], bf[fc], acc[fr][fc], 0, 0, 0);
    }
  }
  __syncthreads();
  float* LF = (float*)smem;
  #pragma unroll
  for (int fr = 0; fr < 2; ++fr){
    int lr = w*32 + fr*16 + q4*4;
    #pragma unroll
    for (int fc = 0; fc < 3; ++fc){
      int col = fc*16 + m16;
      #pragma unroll
      for (int q = 0; q < 4; ++q)
        LF[col*133 + lr + q] = acc[fr][fc][q];
    }
  }
  __syncthreads();
  float* brp = (blockIdx.y < 6) ? brpA + (size_t)blockIdx.y*200000
             : (blockIdx.y == 6) ? brpC : brpD;
  for (int o = t; o < OD*128; o += 256){
    int col = o >> 7, row = o & 127;
    int gr = i0 + row;
    if (gr < VV) brp[(size_t)col*VV + gr] = LF[col*133 + row];
  }
}

// ============ K5r: br = sum of 8 partial slices (6 in Xb + Rn-slice + br-slice) ============
__global__ __launch_bounds__(256) void k5r_red(const float* __restrict__ brpA,
    const float* __restrict__ brpC, const float* __restrict__ brpD,
    float* __restrict__ br){
  int idx = blockIdx.x*256 + threadIdx.x;   // float4 index, 50000 total
  if (idx >= 50000) return;
  const float4* a = (const float4*)brpA;
  float4 s = a[idx];
  #pragma unroll
  for (int sl = 1; sl < 6; ++sl){
    float4 v = a[(size_t)sl*50000 + idx];
    s.x += v.x; s.y += v.y; s.z += v.z; s.w += v.w;
  }
  {
    float4 v = ((const float4*)brpC)[idx];
    s.x += v.x; s.y += v.y; s.z += v.z; s.w += v.w;
  }
  {
    float4 v = ((const float4*)brpD)[idx];   // same region as br: read-before-write per idx
    s.x += v.x; s.y += v.y; s.z += v.z; s.w += v.w;
  }
  ((float4*)br)[idx] = s;
}

// ============ K6: e1pre += br @ W1^T (split-K) + ECR iters 95..99 + final (y==10) ============
__global__ __launch_bounds__(256) void k6_e1(const float* __restrict__ br,
    const float* __restrict__ W1, float* __restrict__ e1pre,
    const __half* __restrict__ Kn, const float* __restrict__ cost,
    float* __restrict__ accg, int* __restrict__ cnt, float* __restrict__ scal){
  __shared__ __align__(16) char smem[34816];
  const int t = threadIdx.x;
  if (blockIdx.y == 10){
    if (blockIdx.x < 16)
      ecr_block(blockIdx.x, 95, 5, true, Kn, cost, accg, cnt, scal, smem);
    return;
  }
  const int lane = t & 63, w = t >> 6;
  const int k = blockIdx.x*4 + w;
  const int f0 = blockIdx.y * 125;       // 10 chunks x 125 float4 = 1250
  float acc[OD];
  #pragma unroll
  for (int i = 0; i < OD; ++i) acc[i] = 0.f;
  const float4* w4p = (const float4*)(W1 + (size_t)k*VV);
  for (int f4 = f0 + lane; f4 < f0 + 125; f4 += 64){
    float4 wv = w4p[f4];
    #pragma unroll
    for (int i = 0; i < OD; ++i){
      float4 bv = ((const float4*)(br + (size_t)i*VV))[f4];
      acc[i] += bv.x*wv.x + bv.y*wv.y + bv.z*wv.z + bv.w*wv.w;
    }
  }
  #pragma unroll
  for (int i = 0; i < OD; ++i)
    #pragma unroll
    for (int off = 32; off; off >>= 1)
      acc[i] += __shfl_down(acc[i], off, 64);
  float (*red)[OD] = (float(*)[OD])smem;
  if (lane == 0){
    #pragma unroll
    for (int i = 0; i < OD; ++i) red[w][i] = acc[i];
  }
  __syncthreads();
  if (t < 160){
    int ww = t / OD, i = t - ww*OD;
    int kk = blockIdx.x*4 + ww;
    atomicAdd(&e1pre[kk*OD + i], red[ww][i]);
  }
}

// ============ K6b: in-place bias + softplus on e1 (8000 elems) ============
__global__ __launch_bounds__(256) void k6b_sp(const float* __restrict__ b1,
    float* __restrict__ e1t){
  int idx = blockIdx.x*256 + threadIdx.x;
  if (idx >= ENH*OD) return;
  int kk = idx / OD;
  float x = e1t[idx] + b1[kk];
  e1t[idx] = (x > 20.f) ? x : log1pf(__expf(x));
}

// ============ K7: e2^T = softplus(e1 @ W2^T + b2) ============
__global__ __launch_bounds__(256) void k7_e2(const float* __restrict__ e1t,
    const float* __restrict__ W2, const float* __restrict__ b2, float* __restrict__ e2t){
  const int t = threadIdx.x;
  const int lane = t & 63, w = t >> 6;
  const int k = blockIdx.x*4 + w;
  float acc[OD];
  #pragma unroll
  for (int i = 0; i < OD; ++i) acc[i] = 0.f;
  for (int j = lane; j < ENH; j += 64){
    float wv = W2[(size_t)k*ENH + j];
    #pragma unroll
    for (int i = 0; i < OD; ++i) acc[i] += e1t[j*OD + i] * wv;
  }
  #pragma unroll
  for (int i = 0; i < OD; ++i)
    #pragma unroll
    for (int off = 32; off; off >>= 1)
      acc[i] += __shfl_down(acc[i], off, 64);
  __shared__ float red[4][OD];
  if (lane == 0){
    #pragma unroll
    for (int i = 0; i < OD; ++i) red[w][i] = acc[i];
  }
  __syncthreads();
  if (t < 160){
    int ww = t / OD, i = t - ww*OD;
    int kk = blockIdx.x*4 + ww;
    float x = red[ww][i] + b2[kk];
    float sp = (x > 20.f) ? x : log1pf(__expf(x));
    e2t[kk*OD + i] = sp;
  }
}

// ============ K8a: mu_pre/lv_pre (stored [t50][i]) ============
__global__ __launch_bounds__(256) void k8a_mulv(const float* __restrict__ e2t,
    const float* __restrict__ Wmu, const float* __restrict__ bmu,
    const float* __restrict__ Wlv, const float* __restrict__ blv,
    float* __restrict__ mupre, float* __restrict__ lvpre){
  int id = blockIdx.x*256 + threadIdx.x;
  if (id >= NTOP*OD) return;
  int t50 = id / OD, i = id - t50*OD;
  float am = 0.f, al = 0.f;
  for (int kk = 0; kk < ENH; ++kk){
    float e = e2t[kk*OD + i];
    am += e * Wmu[t50*ENH + kk];
    al += e * Wlv[t50*ENH + kk];
  }
  mupre[t50*OD + i] = am + bmu[t50];
  lvpre[t50*OD + i] = al + blv[t50];
}

// ============ K8b: BN + KL + z/theta + small SNE(50) + theta_reduced (single WG) ============
__global__ __launch_bounds__(256) void k8b_theta(const float* __restrict__ mupre,
    const float* __restrict__ lvpre,
    const float* __restrict__ g_mu, const float* __restrict__ be_mu,
    const float* __restrict__ g_lv, const float* __restrict__ be_lv,
    const float* __restrict__ eps_noise, const float* __restrict__ projK,
    float* __restrict__ thred, float* __restrict__ d_out3, float* __restrict__ scal){
  __shared__ float mu[NTOP][OD];
  __shared__ float lv[NTOP][OD];
  __shared__ float th[OD][NTOP];
  __shared__ float C2[NTOP][NTOP];
  __shared__ float P2[NTOP][NTOP];
  __shared__ float f2[NTOP], nf[NTOP];
  __shared__ float sred[4];
  __shared__ float eps2s[2];
  const int t = threadIdx.x;
  if (t < NTOP){
    float m = 0.f;
    for (int i = 0; i < OD; ++i) m += mupre[t*OD + i];
    m *= (1.f/OD);
    float v = 0.f;
    for (int i = 0; i < OD; ++i){ float d = mupre[t*OD+i] - m; v += d*d; }
    v *= (1.f/OD);
    float sc = g_mu[t] * rsqrtf(v + 1e-5f);
    float sh = be_mu[t];
    for (int i = 0; i < OD; ++i) mu[t][i] = (mupre[t*OD+i] - m)*sc + sh;
    m = 0.f;
    for (int i = 0; i < OD; ++i) m += lvpre[t*OD + i];
    m *= (1.f/OD);
    v = 0.f;
    for (int i = 0; i < OD; ++i){ float d = lvpre[t*OD+i] - m; v += d*d; }
    v *= (1.f/OD);
    sc = g_lv[t] * rsqrtf(v + 1e-5f);
    sh = be_lv[t];
    for (int i = 0; i < OD; ++i) lv[t][i] = (lvpre[t*OD+i] - m)*sc + sh;
  }
  __syncthreads();
  { // KL divergence
    float kl = 0.f;
    if (t < OD){
      const float var2 = 1.f - 1.f/(float)NTOP;
      const float lv2 = logf(var2);
      float ssum = 0.f;
      for (int q = 0; q < NTOP; ++q){
        float l = lv[q][t];
        float m = mu[q][t];
        ssum += (__expf(l) + m*m)/var2 + lv2 - l;
      }
      kl = 0.5f*(ssum - (float)NTOP);
    }
    #pragma unroll
    for (int off = 32; off; off >>= 1) kl += __shfl_down(kl, off, 64);
    if ((t & 63) == 0) sred[t >> 6] = kl;
    __syncthreads();
    if (t == 0) scal[2] = (sred[0]+sred[1]+sred[2]+sred[3]) * (1.f/OD);
    __syncthreads();
  }
  if (t < OD){ // z + softmax
    float z[NTOP];
    float mx = -1e30f;
    for (int q = 0; q < NTOP; ++q){
      float val = mu[q][t] + eps_noise[t*NTOP + q]*__expf(0.5f*lv[q][t]);
      z[q] = val;
      mx = fmaxf(mx, val);
    }
    float ssum = 0.f;
    for (int q = 0; q < NTOP; ++q){ float e = __expf(z[q]-mx); z[q] = e; ssum += e; }
    float inv = 1.f/ssum;
    for (int q = 0; q < NTOP; ++q) th[t][q] = z[q]*inv;
  }
  __syncthreads();
  { // C2 + mean
    float csum = 0.f;
    for (int pr = t; pr < NTOP*NTOP; pr += 256){
      int a = pr / NTOP, b = pr - (pr/NTOP)*NTOP;
      float ss = 0.f;
      for (int i = 0; i < OD; ++i){ float d = th[i][a] - th[i][b]; ss += d*d; }
      C2[a][b] = ss;
      csum += ss;
    }
    #pragma unroll
    for (int off = 32; off; off >>= 1) csum += __shfl_down(csum, off, 64);
    if ((t & 63) == 0) sred[t >> 6] = csum;
    __syncthreads();
    if (t == 0){
      float meanC = (sred[0]+sred[1]+sred[2]+sred[3]) / ((float)NTOP*NTOP);
      float e2 = meanC / logf(30.f) + 1e-6f;
      eps2s[0] = e2; eps2s[1] = 1.f/e2;
    }
  }
  if (t < NTOP) f2[t] = 0.f;
  __syncthreads();
  const float loga2 = -logf((float)NTOP);
  for (int it = 0; it < 20; ++it){
    if (t < NTOP){
      float ie = eps2s[1];
      float ssum = 0.f;
      for (int sI = 0; sI < NTOP; ++sI)
        ssum += __expf((f2[sI] - C2[t][sI]) * ie);
      float lse = __logf(ssum);
      nf[t] = 0.5f*(f2[t] + eps2s[0]*(loga2 - lse));
    }
    __syncthreads();
    if (t < NTOP) f2[t] = nf[t];
    __syncthreads();
  }
  for (int pr = t; pr < NTOP*NTOP; pr += 256){
    int a = pr / NTOP, b = pr - (pr/NTOP)*NTOP;
    P2[a][b] = __expf((f2[a] + f2[b] - C2[a][b]) * eps2s[1]);
  }
  __syncthreads();
  for (int o = t; o < NTOP*OD; o += 256){
    int t50 = o / OD, kk = o - (o/OD)*OD;
    float ssum = 0.f;
    for (int sI = 0; sI < NTOP; ++sI)
      ssum += P2[t50][sI] * projK[sI*OD + kk];
    thred[kk*NTOP + t50] = ssum;
    d_out3[kk*NTOP + t50] = ssum;
  }
}

// ============ K10: cost, beta=softmax(-5c over topics), Kn=(exp(-5(c-cmin)))^4 fp16 ============
__global__ __launch_bounds__(256) void k10_cost(const float* __restrict__ temb,
    const float* __restrict__ wemb, float* __restrict__ cost, __half* __restrict__ Kn,
    float* __restrict__ beta){
  __shared__ float Tt[100][52];
  __shared__ float wed[100][68];
  __shared__ float sc[52][64];
  __shared__ float tn[52];
  __shared__ float wn[64];
  const int t = threadIdx.x;
  const int j0 = blockIdx.x * 64;
  const int tg = t >> 4, jg = t & 15;
  float am[4][4];
  #pragma unroll
  for (int a = 0; a < 4; ++a)
    #pragma unroll
    for (int b = 0; b < 4; ++b) am[a][b] = 0.f;
  float tnp = 0.f, wnp = 0.f;
  for (int c = 0; c < 2; ++c){
    __syncthreads();
    const int dbase = c*100;
    for (int idx = t; idx < NTOP*100; idx += 256){
      int t50 = idx / 100, d = idx - t50*100;
      Tt[d][t50] = temb[t50*NEMB + dbase + d];
    }
    for (int idx = t; idx < 64*100; idx += 256){
      int j = idx / 100, d = idx - j*100;
      int gj = j0 + j;
      wed[d][j] = (gj < VV) ? wemb[(size_t)gj*NEMB + dbase + d] : 0.f;
    }
    __syncthreads();
    if (t < NTOP){
      float a = 0.f;
      for (int d = 0; d < 100; ++d){ float v = Tt[d][t]; a += v*v; }
      tnp += a;
    }
    if (t >= 64 && t < 128){
      int j = t - 64;
      float a = 0.f;
      for (int d = 0; d < 100; ++d){ float v = wed[d][j]; a += v*v; }
      wnp += a;
    }
    if (t < 208){
      for (int d = 0; d < 100; ++d){
        const float4 tv = *(const float4*)(&Tt[d][tg*4]);
        const float4 wv = *(const float4*)(&wed[d][jg*4]);
        am[0][0] += tv.x*wv.x; am[0][1] += tv.x*wv.y; am[0][2] += tv.x*wv.z; am[0][3] += tv.x*wv.w;
        am[1][0] += tv.y*wv.x; am[1][1] += tv.y*wv.y; am[1][2] += tv.y*wv.z; am[1][3] += tv.y*wv.w;
        am[2][0] += tv.z*wv.x; am[2][1] += tv.z*wv.y; am[2][2] += tv.z*wv.z; am[2][3] += tv.z*wv.w;
        am[3][0] += tv.w*wv.x; am[3][1] += tv.w*wv.y; am[3][2] += tv.w*wv.z; am[3][3] += tv.w*wv.w;
      }
    }
  }
  if (t < NTOP) tn[t] = tnp;
  if (t >= 64 && t < 128) wn[t-64] = wnp;
  __syncthreads();
  if (t < 208){
    #pragma unroll
    for (int a = 0; a < 4; ++a){
      int t50 = tg*4 + a;
      if (t50 < NTOP){
        float tv = tn[t50];
        float cc[4];
        #pragma unroll
        for (int b = 0; b < 4; ++b) cc[b] = tv + wn[jg*4+b] - 2.f*am[a][b];
        int gj = j0 + jg*4;
        if (gj + 3 < VV)
          *(float4*)(cost + (size_t)t50*VV + gj) = make_float4(cc[0],cc[1],cc[2],cc[3]);
        #pragma unroll
        for (int b = 0; b < 4; ++b) sc[t50][jg*4+b] = -5.f*cc[b];
      }
    }
  }
  __syncthreads();
  if (t < 64){
    int gj = j0 + t;
    if (gj < VV){
      float mx = -1e30f;
      for (int q = 0; q < NTOP; ++q) mx = fmaxf(mx, sc[q][t]);
      float ssum = 0.f;
      for (int q = 0; q < NTOP; ++q){ float e = __expf(sc[q][t]-mx); sc[q][t] = e; ssum += e; }
      float inv = 1.f/ssum;
      for (int q = 0; q < NTOP; ++q){
        float e = sc[q][t];
        float e2 = e*e;
        Kn[(size_t)q*KNS + gj] = __float2half(e2*e2);   // exp(-20(c-cmin))
        beta[(size_t)q*VV + gj] = e*inv;
      }
    }
  }
}

// ============ K12: R = theta_red @ beta, column BN ============
__global__ __launch_bounds__(256) void k12_reconA(const float* __restrict__ thred,
    const float* __restrict__ beta, const float* __restrict__ g_dec,
    const float* __restrict__ be_dec, float* __restrict__ Rn){
  __shared__ float trs[OD][NTOP];
  const int t = threadIdx.x;
  for (int o = t; o < OD*NTOP; o += 256) trs[o/NTOP][o - (o/NTOP)*NTOP] = thred[o];
  __syncthreads();
  int j = blockIdx.x*256 + t;
  if (j >= VV) return;
  float a[OD];
  #pragma unroll
  for (int i = 0; i < OD; ++i) a[i] = 0.f;
  for (int q = 0; q < NTOP; ++q){
    float bv = beta[(size_t)q*VV + j];
    #pragma unroll
    for (int i = 0; i < OD; ++i) a[i] += trs[i][q]*bv;
  }
  float m = 0.f;
  #pragma unroll
  for (int i = 0; i < OD; ++i) m += a[i];
  m *= (1.f/OD);
  float v = 0.f;
  #pragma unroll
  for (int i = 0; i < OD; ++i){ float d = a[i]-m; v += d*d; }
  v *= (1.f/OD);
  float scale = g_dec[j]*rsqrtf(v + 1e-5f);
  float sh = be_dec[j];
  #pragma unroll
  for (int i = 0; i < OD; ++i) Rn[(size_t)i*VV + j] = (a[i]-m)*scale + sh;
}

// ============ K13: per-row sums for softmax + cross-entropy ============
__global__ __launch_bounds__(256) void k13_reconB(const float* __restrict__ Rn,
    const float* __restrict__ br, float* __restrict__ rows){
  const int i = blockIdx.x;
  const int t = threadIdx.x;
  float s1 = 0.f, s2 = 0.f, s3 = 0.f;
  for (int j = t; j < VV; j += 256){
    float rn = Rn[(size_t)i*VV + j];
    float bv = br[(size_t)i*VV + j];
    s1 += __expf(rn);
    s2 += bv*rn;
    s3 += bv;
  }
  #pragma unroll
  for (int off = 32; off; off >>= 1){
    s1 += __shfl_down(s1, off, 64);
    s2 += __shfl_down(s2, off, 64);
    s3 += __shfl_down(s3, off, 64);
  }
  __shared__ float red[3][4];
  int lane = t & 63, w = t >> 6;
  if (lane == 0){ red[0][w] = s1; red[1][w] = s2; red[2][w] = s3; }
  __syncthreads();
  if (t == 0){
    rows[i]      = red[0][0]+red[0][1]+red[0][2]+red[0][3];
    rows[40 + i] = red[1][0]+red[1][1]+red[1][2]+red[1][3];
    rows[80 + i] = red[2][0]+red[2][1]+red[2][2]+red[2][3];
  }
}

// ============ K14: final losses ============
__global__ void k14_final(const float* __restrict__ rows, const float* __restrict__ scal,
    float* __restrict__ out){
  const int t = threadIdx.x;
  float v = 0.f;
  if (t < OD) v = rows[40 + t] - logf(rows[t]) * rows[80 + t];
  #pragma unroll
  for (int off = 32; off; off >>= 1) v += __shfl_down(v, off, 64);
  if (t == 0){
    float recon = -v * (1.f/OD);
    float tm = recon + scal[2];
    float ecr = 250.f * scal[3];
    out[0] = tm + ecr;
    out[1] = tm;
    out[2] = ecr;
  }
}

extern "C" void kernel_launch(void* const* d_in, const int* in_sizes, int n_in,
                              void* d_out, int out_size, void* d_ws, size_t ws_size,
                              hipStream_t stream){
  const float* bow   = (const float*)d_in[0];
  const float* epsn  = (const float*)d_in[1];
  const float* W1    = (const float*)d_in[2];
  const float* b1    = (const float*)d_in[3];
  const float* W2    = (const float*)d_in[4];
  const float* b2    = (const float*)d_in[5];
  const float* Wmu   = (const float*)d_in[6];
  const float* bmu   = (const float*)d_in[7];
  const float* Wlv   = (const float*)d_in[8];
  const float* blv   = (const float*)d_in[9];
  const float* g_mu  = (const float*)d_in[10];
  const float* be_mu = (const float*)d_in[11];
  const float* g_lv  = (const float*)d_in[12];
  const float* be_lv = (const float*)d_in[13];
  const float* g_dec = (const float*)d_in[14];
  const float* be_dec= (const float*)d_in[15];
  const float* wemb  = (const float*)d_in[16];
  const float* temb  = (const float*)d_in[17];
  const float* projV = (const float*)d_in[18];
  const float* projK = (const float*)d_in[19];
  char* ws = (char*)d_ws;
  float* r     = (float*)(ws + OFF_R);
  float* s     = (float*)(ws + OFF_S);
  float* scal  = (float*)(ws + OFF_SCAL);
  float* phiA  = (float*)(ws + OFF_PHIA);
  float* phiB  = (float*)(ws + OFF_PHIB);
  float* rows  = (float*)(ws + OFF_ROWS);
  float* accg  = (float*)(ws + OFF_PARTS);
  int*   cnt   = (int*)(ws + OFF_FLAGS);
  float* mupre = (float*)(ws + OFF_MUPRE);
  float* lvpre = (float*)(ws + OFF_LVPRE);
  float* e1t   = (float*)(ws + OFF_E1T);
  float* e2t   = (float*)(ws + OFF_E2T);
  float* thred = (float*)(ws + OFF_THRED);
  float* br    = (float*)(ws + OFF_BOWRED);
  __hip_bfloat16* pvt = (__hip_bfloat16*)(ws + OFF_PVT);
  __hip_bfloat16* Xb  = (__hip_bfloat16*)(ws + OFF_XB);
  __half* Ce   = (__half*)(ws + OFF_CE);
  float* cost  = (float*)(ws + OFF_COST);
  __half* Kn   = (__half*)(ws + OFF_KM);
  float* beta  = (float*)(ws + OFF_BETA);
  float* Rn    = (float*)(ws + OFF_RN);
  float* sbuf0 = (float*)(ws + OFF_RN);              // sweep rowsum tri-buffer
  float* sbuf1 = (float*)(ws + OFF_RN + 20224);
  float* sbuf2 = (float*)(ws + OFF_RN + 40448);
  float* sbuf[3] = {sbuf0, sbuf1, sbuf2};
  float* P2b[2] = {phiA, phiB};                      // phi^(k) in P2b[k&1]
  float* brpA  = (float*)(ws + OFF_XB);      // 6 slices, Xb dead after k3
  float* brpC  = (float*)(ws + OFF_RN);      // slice 6: Rn region (sbuf dead by k5)
  float* brpD  = (float*)(ws + OFF_BOWRED);  // slice 7: br region (k5r read-then-write)
  float* out   = (float*)d_out;

  hipMemsetAsync(d_ws, 0, ZERO_BYTES, stream);
  hipMemsetAsync(ws + OFF_RN, 0, 60672, stream);   // sweep rowsum tri-buffer
  // ECR prerequisites first (inputs only), so ECR blocks can ride everything after.
  k10_cost<<<79, 256, 0, stream>>>(temb, wemb, cost, Kn, beta);
  // ECR iters 0..9 ride k1 (16 blocks at x=40,41).
  k1_stats<<<dim3(42, 8), 256, 0, stream>>>(bow, Xb, r, s, Kn, cost, accg, cnt, scal);
  k2_eps<<<1, 256, 0, stream>>>(r, s, scal);
  // ECR iters 10..21 ride the SYRK Ce GEMM (window ~50us now fits only 12 iters).
  k3_gemm_ecr<<<836, 256, 0, stream>>>(Xb, r, scal, Ce, Kn, cost, accg, cnt);
  // 20 symmetric sweeps; ECR 22..81 (THREE per launch, ~= the ~10us sweep window).
  for (int g = 0; g < 20; ++g){
    k4_symsweep<<<836, 256, 0, stream>>>(Ce,
        P2b[(g+1)&1] /* phi^(g-1); unused at g=0 */, P2b[g&1] /* phi^(g) out */,
        sbuf[g%3], sbuf[(g+1)%3], sbuf[(g+2)%3],
        Kn, cost, accg, cnt, scal, 22 + 3*g, g);
  }
  // blocks 0..19: phi^(20) from (phi^(19)=phiB, ssum^(19)=sbuf[2]) -> phiA; rest: pvt.
  k5p_pvt<<<980, 256, 0, stream>>>(projV, pvt, phiB, sbuf[2], phiA);
  // ECR iters 82..94 ride k5 (16 blocks at x=40,41).
  k5_bowred<<<dim3(42, 8), 256, 0, stream>>>(Ce, phiA, pvt, brpA, brpC, brpD,
                                             Kn, cost, accg, cnt, scal);
  k5r_red<<<196, 256, 0, stream>>>(brpA, brpC, brpD, br);
  // ECR iters 95..99 + final dot ride k6 (y==10 row).
  k6_e1<<<dim3(50, 11), 256, 0, stream>>>(br, W1, e1t, Kn, cost, accg, cnt, scal);
  k6b_sp<<<32, 256, 0, stream>>>(b1, e1t);
  k7_e2<<<50, 256, 0, stream>>>(e1t, W2, b2, e2t);
  k8a_mulv<<<8, 256, 0, stream>>>(e2t, Wmu, bmu, Wlv, blv, mupre, lvpre);
  k8b_theta<<<1, 256, 0, stream>>>(mupre, lvpre, g_mu, be_mu, g_lv, be_lv,
                                   epsn, projK, thred, out + 3, scal);
  k12_reconA<<<20, 256, 0, stream>>>(thred, beta, g_dec, be_dec, Rn);
  k13_reconB<<<40, 256, 0, stream>>>(Rn, br, rows);
  k14_final<<<1, 64, 0, stream>>>(rows, scal, out);
}